// Round 1
// baseline (1147.404 us; speedup 1.0000x reference)
//
#include <hip/hip_runtime.h>
#include <math.h>

#define N_NODES 50000
#define E_EDGES 800000
#define IN_CH   128
#define C_CH    32
#define H_HEADS 8
#define HC      256      // H_HEADS * C_CH
#define BN_EPS  1e-5f
#define SLOPE   0.2f

// ---------------- CSR build ----------------

__global__ void k_init_deg(int* deg, int n) {
    int i = blockIdx.x * blockDim.x + threadIdx.x;
    if (i < n) deg[i] = 1;              // self-loop contributes 1
}

__global__ void k_hist(const int* __restrict__ dst, int* deg, int e) {
    int i = blockIdx.x * blockDim.x + threadIdx.x;
    if (i < e) atomicAdd(&deg[dst[i]], 1);
}

// single-block exclusive scan of deg[0..n-1] -> row_ptr[0..n], cursor copy
__global__ void k_scan(const int* __restrict__ deg, int* row_ptr, int* cursor, int n) {
    __shared__ int part[1024];
    int tid = threadIdx.x;
    int per = (n + 1023) >> 10;
    int start = tid * per;
    int end = min(start + per, n);
    int s = 0;
    for (int i = start; i < end; ++i) s += deg[i];
    part[tid] = s;
    __syncthreads();
    for (int off = 1; off < 1024; off <<= 1) {
        int u = 0;
        if (tid >= off) u = part[tid - off];
        __syncthreads();
        part[tid] += u;
        __syncthreads();
    }
    int run = part[tid] - s;            // exclusive prefix for this chunk
    for (int i = start; i < end; ++i) {
        row_ptr[i] = run;
        cursor[i] = run;
        run += deg[i];
    }
    if (tid == 1023) row_ptr[n] = part[1023];
}

__global__ void k_fill(const int* __restrict__ src, const int* __restrict__ dst,
                       int* cursor, int* csr_src, int e, int n) {
    int i = blockIdx.x * blockDim.x + threadIdx.x;
    if (i < e) {
        int d = dst[i];
        int p = atomicAdd(&cursor[d], 1);
        csr_src[p] = src[i];
    } else if (i < e + n) {
        int v = i - e;                  // self loop
        int p = atomicAdd(&cursor[v], 1);
        csr_src[p] = v;
    }
}

// ---------------- fp32 GEMM: C0 = A@W0, C1 = A@W1 (blockIdx.z picks) ----------------
// A [M,K] row-major, W [K,Nout] row-major. 64x64 tile, 4x4 per thread.

__global__ __launch_bounds__(256) void k_gemm2(
        const float* __restrict__ A,
        const float* __restrict__ W0, const float* __restrict__ W1,
        float* __restrict__ C0, float* __restrict__ C1,
        int M, int K, int Nout) {
    const float* W = blockIdx.z ? W1 : W0;
    float* Cd = blockIdx.z ? C1 : C0;
    __shared__ float As[16][68];
    __shared__ float Bs[16][68];
    int tid = threadIdx.x;
    int rowBase = blockIdx.x * 64;
    int colBase = blockIdx.y * 64;
    int tx = tid & 15, ty = tid >> 4;
    float acc[4][4] = {};
    for (int k0 = 0; k0 < K; k0 += 16) {
        #pragma unroll
        for (int i = 0; i < 4; ++i) {
            int l = tid + i * 256;
            int kk = l & 15, m = l >> 4;
            int r = rowBase + m;
            As[kk][m] = (r < M) ? A[(size_t)r * K + k0 + kk] : 0.f;
        }
        #pragma unroll
        for (int i = 0; i < 4; ++i) {
            int l = tid + i * 256;
            int nn = l & 63, kk = l >> 6;
            Bs[kk][nn] = W[(size_t)(k0 + kk) * Nout + colBase + nn];
        }
        __syncthreads();
        #pragma unroll
        for (int kk = 0; kk < 16; ++kk) {
            float4 a4 = *(const float4*)&As[kk][ty * 4];
            float4 b4 = *(const float4*)&Bs[kk][tx * 4];
            float av[4] = {a4.x, a4.y, a4.z, a4.w};
            float bv[4] = {b4.x, b4.y, b4.z, b4.w};
            #pragma unroll
            for (int i = 0; i < 4; ++i)
                #pragma unroll
                for (int j = 0; j < 4; ++j)
                    acc[i][j] = fmaf(av[i], bv[j], acc[i][j]);
        }
        __syncthreads();
    }
    #pragma unroll
    for (int i = 0; i < 4; ++i) {
        int r = rowBase + ty * 4 + i;
        if (r < M) {
            #pragma unroll
            for (int j = 0; j < 4; ++j)
                Cd[(size_t)r * Nout + colBase + tx * 4 + j] = acc[i][j];
        }
    }
}

// ---------------- edge pass, layer 0 (concat + bias + BN + ELU) ----------------
// one block (256 threads) per node; thread t handles (h=t>>5, c=t&31)

__global__ __launch_bounds__(256) void k_edge0(
        const float* __restrict__ xl, const float* __restrict__ xr,
        const float* __restrict__ att,
        const int* __restrict__ row_ptr, const int* __restrict__ csr_src,
        const float* __restrict__ b0, const float* __restrict__ g0,
        const float* __restrict__ be0, const float* __restrict__ m0,
        const float* __restrict__ v0,
        float* __restrict__ hout) {
    int i = blockIdx.x;
    int tid = threadIdx.x;
    float xr_v = xr[(size_t)i * HC + tid];
    float att_v = att[tid];
    int beg = row_ptr[i], end = row_ptr[i + 1];
    float M = -INFINITY, S = 0.f, acc = 0.f;
    for (int j = beg; j < end; ++j) {
        int s = csr_src[j];
        float xv = xl[(size_t)s * HC + tid];
        float e = xv + xr_v;
        e = e > 0.f ? e : SLOPE * e;
        float p = e * att_v;
        p += __shfl_xor(p, 16);
        p += __shfl_xor(p, 8);
        p += __shfl_xor(p, 4);
        p += __shfl_xor(p, 2);
        p += __shfl_xor(p, 1);
        float nM = fmaxf(M, p);
        float f = __expf(M - nM);
        float w = __expf(p - nM);
        S = S * f + w;
        acc = acc * f + w * xv;
        M = nM;
    }
    float r = acc / S + b0[tid];
    r = (r - m0[tid]) * rsqrtf(v0[tid] + BN_EPS) * g0[tid] + be0[tid];
    r = r > 0.f ? r : expm1f(r);
    hout[(size_t)i * HC + tid] = r;
}

// ---------------- edge pass, layer 1 (head-mean + bias + BN + classifier) ----------------

__global__ __launch_bounds__(256) void k_edge1(
        const float* __restrict__ xl, const float* __restrict__ xr,
        const float* __restrict__ att,
        const int* __restrict__ row_ptr, const int* __restrict__ csr_src,
        const float* __restrict__ b1, const float* __restrict__ g1,
        const float* __restrict__ be1, const float* __restrict__ m1,
        const float* __restrict__ v1,
        const float* __restrict__ Wc, const float* __restrict__ bc,
        float* __restrict__ out) {
    int i = blockIdx.x;
    int tid = threadIdx.x;
    float xr_v = xr[(size_t)i * HC + tid];
    float att_v = att[tid];
    int beg = row_ptr[i], end = row_ptr[i + 1];
    float M = -INFINITY, S = 0.f, acc = 0.f;
    for (int j = beg; j < end; ++j) {
        int s = csr_src[j];
        float xv = xl[(size_t)s * HC + tid];
        float e = xv + xr_v;
        e = e > 0.f ? e : SLOPE * e;
        float p = e * att_v;
        p += __shfl_xor(p, 16);
        p += __shfl_xor(p, 8);
        p += __shfl_xor(p, 4);
        p += __shfl_xor(p, 2);
        p += __shfl_xor(p, 1);
        float nM = fmaxf(M, p);
        float f = __expf(M - nM);
        float w = __expf(p - nM);
        S = S * f + w;
        acc = acc * f + w * xv;
        M = nM;
    }
    __shared__ float sm[HC];
    sm[tid] = acc / S;
    __syncthreads();
    if (tid < C_CH) {
        float s = 0.f;
        #pragma unroll
        for (int hh = 0; hh < H_HEADS; ++hh) s += sm[hh * C_CH + tid];
        s = s * (1.f / H_HEADS) + b1[tid];
        s = (s - m1[tid]) * rsqrtf(v1[tid] + BN_EPS) * g1[tid] + be1[tid];
        sm[tid] = s;
    }
    __syncthreads();
    if (tid < 2) {
        float o = bc[tid];
        #pragma unroll
        for (int c = 0; c < C_CH; ++c) o += sm[c] * Wc[c * 2 + tid];
        out[(size_t)i * 2 + tid] = o;
    }
}

// ---------------- launcher ----------------

extern "C" void kernel_launch(void* const* d_in, const int* in_sizes, int n_in,
                              void* d_out, int out_size, void* d_ws, size_t ws_size,
                              hipStream_t stream) {
    const float* x    = (const float*)d_in[0];
    const int*   ei   = (const int*)d_in[1];
    const float* Wl0  = (const float*)d_in[2];
    const float* Wr0  = (const float*)d_in[3];
    const float* att0 = (const float*)d_in[4];
    const float* b0   = (const float*)d_in[5];
    const float* g0   = (const float*)d_in[6];
    const float* be0  = (const float*)d_in[7];
    const float* m0   = (const float*)d_in[8];
    const float* v0   = (const float*)d_in[9];
    const float* Wl1  = (const float*)d_in[10];
    const float* Wr1  = (const float*)d_in[11];
    const float* att1 = (const float*)d_in[12];
    const float* b1   = (const float*)d_in[13];
    const float* g1   = (const float*)d_in[14];
    const float* be1  = (const float*)d_in[15];
    const float* m1   = (const float*)d_in[16];
    const float* v1   = (const float*)d_in[17];
    const float* Wc   = (const float*)d_in[18];
    const float* bc   = (const float*)d_in[19];
    float* out = (float*)d_out;

    const int N = N_NODES, E = E_EDGES;
    const int* srcp = ei;        // edge_index[0]
    const int* dstp = ei + E;    // edge_index[1]

    float* bufA = (float*)d_ws;                       // xl   [N,256]
    float* bufB = bufA + (size_t)N * HC;              // xr   [N,256]
    float* bufC = bufB + (size_t)N * HC;              // h0   [N,256]
    int* deg     = (int*)(bufC + (size_t)N * HC);
    int* row_ptr = deg + N;
    int* cursor  = row_ptr + (N + 1);
    int* csr_src = cursor + N;                        // E+N entries

    // CSR build (by dst)
    k_init_deg<<<(N + 255) / 256, 256, 0, stream>>>(deg, N);
    k_hist<<<(E + 255) / 256, 256, 0, stream>>>(dstp, deg, E);
    k_scan<<<1, 1024, 0, stream>>>(deg, row_ptr, cursor, N);
    k_fill<<<(E + N + 255) / 256, 256, 0, stream>>>(srcp, dstp, cursor, csr_src, E, N);

    dim3 ggrid((N + 63) / 64, HC / 64, 2);
    // layer 0 projections: xl0 = x@Wl0, xr0 = x@Wr0
    k_gemm2<<<ggrid, 256, 0, stream>>>(x, Wl0, Wr0, bufA, bufB, N, IN_CH, HC);
    // layer 0 edge pass + BN + ELU -> bufC
    k_edge0<<<N, 256, 0, stream>>>(bufA, bufB, att0, row_ptr, csr_src,
                                   b0, g0, be0, m0, v0, bufC);
    // layer 1 projections: xl1 = h0@Wl1, xr1 = h0@Wr1
    k_gemm2<<<ggrid, 256, 0, stream>>>(bufC, Wl1, Wr1, bufA, bufB, N, HC, HC);
    // layer 1 edge pass + head-mean + BN + classifier -> out
    k_edge1<<<N, 256, 0, stream>>>(bufA, bufB, att1, row_ptr, csr_src,
                                   b1, g1, be1, m1, v1, Wc, bc, out);
}

// Round 2
// 955.364 us; speedup vs baseline: 1.2010x; 1.2010x over previous
//
#include <hip/hip_runtime.h>
#include <math.h>

#define N_NODES 50000
#define E_EDGES 800000
#define IN_CH   128
#define C_CH    32
#define H_HEADS 8
#define HC      256      // H_HEADS * C_CH
#define BN_EPS  1e-5f
#define SLOPE   0.2f

// ---------------- CSR build ----------------

__global__ void k_init_deg(int* deg, int n) {
    int i = blockIdx.x * blockDim.x + threadIdx.x;
    if (i < n) deg[i] = 1;              // self-loop contributes 1
}

__global__ void k_hist(const int* __restrict__ dst, int* deg, int e) {
    int i = blockIdx.x * blockDim.x + threadIdx.x;
    if (i < e) atomicAdd(&deg[dst[i]], 1);
}

// single-block exclusive scan of deg[0..n-1] -> row_ptr[0..n], cursor copy
__global__ void k_scan(const int* __restrict__ deg, int* row_ptr, int* cursor, int n) {
    __shared__ int part[1024];
    int tid = threadIdx.x;
    int per = (n + 1023) >> 10;
    int start = tid * per;
    int end = min(start + per, n);
    int s = 0;
    for (int i = start; i < end; ++i) s += deg[i];
    part[tid] = s;
    __syncthreads();
    for (int off = 1; off < 1024; off <<= 1) {
        int u = 0;
        if (tid >= off) u = part[tid - off];
        __syncthreads();
        part[tid] += u;
        __syncthreads();
    }
    int run = part[tid] - s;            // exclusive prefix for this chunk
    for (int i = start; i < end; ++i) {
        row_ptr[i] = run;
        cursor[i] = run;
        run += deg[i];
    }
    if (tid == 1023) row_ptr[n] = part[1023];
}

__global__ void k_fill(const int* __restrict__ src, const int* __restrict__ dst,
                       int* cursor, int* csr_src, int e, int n) {
    int i = blockIdx.x * blockDim.x + threadIdx.x;
    if (i < e) {
        int d = dst[i];
        int p = atomicAdd(&cursor[d], 1);
        csr_src[p] = src[i];
    } else if (i < e + n) {
        int v = i - e;                  // self loop
        int p = atomicAdd(&cursor[v], 1);
        csr_src[p] = v;
    }
}

// ---------------- fp32 GEMM: C0 = A@W0, C1 = A@W1 (blockIdx.z picks) ----------------
// A [M,K] row-major, W [K,Nout] row-major. 64x64 tile, 4x4 per thread.

__global__ __launch_bounds__(256) void k_gemm2(
        const float* __restrict__ A,
        const float* __restrict__ W0, const float* __restrict__ W1,
        float* __restrict__ C0, float* __restrict__ C1,
        int M, int K, int Nout) {
    const float* W = blockIdx.z ? W1 : W0;
    float* Cd = blockIdx.z ? C1 : C0;
    __shared__ float As[16][68];
    __shared__ float Bs[16][68];
    int tid = threadIdx.x;
    int rowBase = blockIdx.x * 64;
    int colBase = blockIdx.y * 64;
    int tx = tid & 15, ty = tid >> 4;
    float acc[4][4] = {};
    for (int k0 = 0; k0 < K; k0 += 16) {
        #pragma unroll
        for (int i = 0; i < 4; ++i) {
            int l = tid + i * 256;
            int kk = l & 15, m = l >> 4;
            int r = rowBase + m;
            As[kk][m] = (r < M) ? A[(size_t)r * K + k0 + kk] : 0.f;
        }
        #pragma unroll
        for (int i = 0; i < 4; ++i) {
            int l = tid + i * 256;
            int nn = l & 63, kk = l >> 6;
            Bs[kk][nn] = W[(size_t)(k0 + kk) * Nout + colBase + nn];
        }
        __syncthreads();
        #pragma unroll
        for (int kk = 0; kk < 16; ++kk) {
            float4 a4 = *(const float4*)&As[kk][ty * 4];
            float4 b4 = *(const float4*)&Bs[kk][tx * 4];
            float av[4] = {a4.x, a4.y, a4.z, a4.w};
            float bv[4] = {b4.x, b4.y, b4.z, b4.w};
            #pragma unroll
            for (int i = 0; i < 4; ++i)
                #pragma unroll
                for (int j = 0; j < 4; ++j)
                    acc[i][j] = fmaf(av[i], bv[j], acc[i][j]);
        }
        __syncthreads();
    }
    #pragma unroll
    for (int i = 0; i < 4; ++i) {
        int r = rowBase + ty * 4 + i;
        if (r < M) {
            #pragma unroll
            for (int j = 0; j < 4; ++j)
                Cd[(size_t)r * Nout + colBase + tx * 4 + j] = acc[i][j];
        }
    }
}

// ---------------- edge accumulation core ----------------
// 32-lane (head-group) reduction
__device__ __forceinline__ float red32(float p) {
    p += __shfl_xor(p, 16);
    p += __shfl_xor(p, 8);
    p += __shfl_xor(p, 4);
    p += __shfl_xor(p, 2);
    p += __shfl_xor(p, 1);
    return p;
}

// Softmax-weighted gather-sum over incoming edges of node i.
// No running max: logits are O(1)-scale (att . LeakyReLU of unit-scale data),
// exp cannot overflow fp32; this breaks the loop-carried rescale chain.
// Unroll-4: batch the 4 gathers so load latency overlaps the 4 independent
// logit/exp chains.
__device__ __forceinline__ float edge_accum(
        const float* __restrict__ xl, float xr_v, float att_v,
        const int* __restrict__ csr_src, int beg, int end, int tid) {
    float S = 0.f, acc = 0.f;
    int j = beg;
    for (; j + 4 <= end; j += 4) {
        int s0 = csr_src[j];
        int s1 = csr_src[j + 1];
        int s2 = csr_src[j + 2];
        int s3 = csr_src[j + 3];
        float x0 = xl[(size_t)s0 * HC + tid];
        float x1 = xl[(size_t)s1 * HC + tid];
        float x2 = xl[(size_t)s2 * HC + tid];
        float x3 = xl[(size_t)s3 * HC + tid];
        float e0 = x0 + xr_v; e0 = e0 > 0.f ? e0 : SLOPE * e0;
        float e1 = x1 + xr_v; e1 = e1 > 0.f ? e1 : SLOPE * e1;
        float e2 = x2 + xr_v; e2 = e2 > 0.f ? e2 : SLOPE * e2;
        float e3 = x3 + xr_v; e3 = e3 > 0.f ? e3 : SLOPE * e3;
        float p0 = red32(e0 * att_v);
        float p1 = red32(e1 * att_v);
        float p2 = red32(e2 * att_v);
        float p3 = red32(e3 * att_v);
        float w0 = __expf(p0);
        float w1 = __expf(p1);
        float w2 = __expf(p2);
        float w3 = __expf(p3);
        S += (w0 + w1) + (w2 + w3);
        acc = fmaf(w0, x0, acc);
        acc = fmaf(w1, x1, acc);
        acc = fmaf(w2, x2, acc);
        acc = fmaf(w3, x3, acc);
    }
    for (; j < end; ++j) {
        int s = csr_src[j];
        float xv = xl[(size_t)s * HC + tid];
        float e = xv + xr_v;
        e = e > 0.f ? e : SLOPE * e;
        float w = __expf(red32(e * att_v));
        S += w;
        acc = fmaf(w, xv, acc);
    }
    return acc / S;
}

// ---------------- edge pass, layer 0 (concat + bias + BN + ELU) ----------------
// one block (256 threads) per node; thread t handles (h=t>>5, c=t&31)

__global__ __launch_bounds__(256) void k_edge0(
        const float* __restrict__ xl, const float* __restrict__ xr,
        const float* __restrict__ att,
        const int* __restrict__ row_ptr, const int* __restrict__ csr_src,
        const float* __restrict__ b0, const float* __restrict__ g0,
        const float* __restrict__ be0, const float* __restrict__ m0,
        const float* __restrict__ v0,
        float* __restrict__ hout) {
    int i = blockIdx.x;
    int tid = threadIdx.x;
    float xr_v = xr[(size_t)i * HC + tid];
    float att_v = att[tid];
    int beg = row_ptr[i], end = row_ptr[i + 1];
    float r = edge_accum(xl, xr_v, att_v, csr_src, beg, end, tid) + b0[tid];
    r = (r - m0[tid]) * rsqrtf(v0[tid] + BN_EPS) * g0[tid] + be0[tid];
    r = r > 0.f ? r : expm1f(r);
    hout[(size_t)i * HC + tid] = r;
}

// ---------------- edge pass, layer 1 (head-mean + bias + BN + classifier) ----------------

__global__ __launch_bounds__(256) void k_edge1(
        const float* __restrict__ xl, const float* __restrict__ xr,
        const float* __restrict__ att,
        const int* __restrict__ row_ptr, const int* __restrict__ csr_src,
        const float* __restrict__ b1, const float* __restrict__ g1,
        const float* __restrict__ be1, const float* __restrict__ m1,
        const float* __restrict__ v1,
        const float* __restrict__ Wc, const float* __restrict__ bc,
        float* __restrict__ out) {
    int i = blockIdx.x;
    int tid = threadIdx.x;
    float xr_v = xr[(size_t)i * HC + tid];
    float att_v = att[tid];
    int beg = row_ptr[i], end = row_ptr[i + 1];
    float r = edge_accum(xl, xr_v, att_v, csr_src, beg, end, tid);
    __shared__ float sm[HC];
    sm[tid] = r;
    __syncthreads();
    if (tid < C_CH) {
        float s = 0.f;
        #pragma unroll
        for (int hh = 0; hh < H_HEADS; ++hh) s += sm[hh * C_CH + tid];
        s = s * (1.f / H_HEADS) + b1[tid];
        s = (s - m1[tid]) * rsqrtf(v1[tid] + BN_EPS) * g1[tid] + be1[tid];
        sm[tid] = s;
    }
    __syncthreads();
    if (tid < 2) {
        float o = bc[tid];
        #pragma unroll
        for (int c = 0; c < C_CH; ++c) o += sm[c] * Wc[c * 2 + tid];
        out[(size_t)i * 2 + tid] = o;
    }
}

// ---------------- launcher ----------------

extern "C" void kernel_launch(void* const* d_in, const int* in_sizes, int n_in,
                              void* d_out, int out_size, void* d_ws, size_t ws_size,
                              hipStream_t stream) {
    const float* x    = (const float*)d_in[0];
    const int*   ei   = (const int*)d_in[1];
    const float* Wl0  = (const float*)d_in[2];
    const float* Wr0  = (const float*)d_in[3];
    const float* att0 = (const float*)d_in[4];
    const float* b0   = (const float*)d_in[5];
    const float* g0   = (const float*)d_in[6];
    const float* be0  = (const float*)d_in[7];
    const float* m0   = (const float*)d_in[8];
    const float* v0   = (const float*)d_in[9];
    const float* Wl1  = (const float*)d_in[10];
    const float* Wr1  = (const float*)d_in[11];
    const float* att1 = (const float*)d_in[12];
    const float* b1   = (const float*)d_in[13];
    const float* g1   = (const float*)d_in[14];
    const float* be1  = (const float*)d_in[15];
    const float* m1   = (const float*)d_in[16];
    const float* v1   = (const float*)d_in[17];
    const float* Wc   = (const float*)d_in[18];
    const float* bc   = (const float*)d_in[19];
    float* out = (float*)d_out;

    const int N = N_NODES, E = E_EDGES;
    const int* srcp = ei;        // edge_index[0]
    const int* dstp = ei + E;    // edge_index[1]

    float* bufA = (float*)d_ws;                       // xl   [N,256]
    float* bufB = bufA + (size_t)N * HC;              // xr   [N,256]
    float* bufC = bufB + (size_t)N * HC;              // h0   [N,256]
    int* deg     = (int*)(bufC + (size_t)N * HC);
    int* row_ptr = deg + N;
    int* cursor  = row_ptr + (N + 1);
    int* csr_src = cursor + N;                        // E+N entries

    // CSR build (by dst)
    k_init_deg<<<(N + 255) / 256, 256, 0, stream>>>(deg, N);
    k_hist<<<(E + 255) / 256, 256, 0, stream>>>(dstp, deg, E);
    k_scan<<<1, 1024, 0, stream>>>(deg, row_ptr, cursor, N);
    k_fill<<<(E + N + 255) / 256, 256, 0, stream>>>(srcp, dstp, cursor, csr_src, E, N);

    dim3 ggrid((N + 63) / 64, HC / 64, 2);
    // layer 0 projections: xl0 = x@Wl0, xr0 = x@Wr0
    k_gemm2<<<ggrid, 256, 0, stream>>>(x, Wl0, Wr0, bufA, bufB, N, IN_CH, HC);
    // layer 0 edge pass + BN + ELU -> bufC
    k_edge0<<<N, 256, 0, stream>>>(bufA, bufB, att0, row_ptr, csr_src,
                                   b0, g0, be0, m0, v0, bufC);
    // layer 1 projections: xl1 = h0@Wl1, xr1 = h0@Wr1
    k_gemm2<<<ggrid, 256, 0, stream>>>(bufC, Wl1, Wr1, bufA, bufB, N, HC, HC);
    // layer 1 edge pass + head-mean + BN + classifier -> out
    k_edge1<<<N, 256, 0, stream>>>(bufA, bufB, att1, row_ptr, csr_src,
                                   b1, g1, be1, m1, v1, Wc, bc, out);
}

// Round 3
// 815.894 us; speedup vs baseline: 1.4063x; 1.1709x over previous
//
#include <hip/hip_runtime.h>
#include <math.h>

#define N_NODES 50000
#define E_EDGES 800000
#define IN_CH   128
#define C_CH    32
#define H_HEADS 8
#define HC      256      // H_HEADS * C_CH
#define BN_EPS  1e-5f
#define SLOPE   0.2f

// ---------------- CSR build ----------------

__global__ void k_init_deg(int* deg, int n) {
    int i = blockIdx.x * blockDim.x + threadIdx.x;
    if (i < n) deg[i] = 1;              // self-loop contributes 1
}

__global__ void k_hist(const int* __restrict__ dst, int* deg, int e) {
    int i = blockIdx.x * blockDim.x + threadIdx.x;
    if (i < e) atomicAdd(&deg[dst[i]], 1);
}

// single-block exclusive scan of deg[0..n-1] -> row_ptr[0..n], cursor copy
__global__ void k_scan(const int* __restrict__ deg, int* row_ptr, int* cursor, int n) {
    __shared__ int part[1024];
    int tid = threadIdx.x;
    int per = (n + 1023) >> 10;
    int start = tid * per;
    int end = min(start + per, n);
    int s = 0;
    for (int i = start; i < end; ++i) s += deg[i];
    part[tid] = s;
    __syncthreads();
    for (int off = 1; off < 1024; off <<= 1) {
        int u = 0;
        if (tid >= off) u = part[tid - off];
        __syncthreads();
        part[tid] += u;
        __syncthreads();
    }
    int run = part[tid] - s;            // exclusive prefix for this chunk
    for (int i = start; i < end; ++i) {
        row_ptr[i] = run;
        cursor[i] = run;
        run += deg[i];
    }
    if (tid == 1023) row_ptr[n] = part[1023];
}

__global__ void k_fill(const int* __restrict__ src, const int* __restrict__ dst,
                       int* cursor, int* csr_src, int e, int n) {
    int i = blockIdx.x * blockDim.x + threadIdx.x;
    if (i < e) {
        int d = dst[i];
        int p = atomicAdd(&cursor[d], 1);
        csr_src[p] = src[i];
    } else if (i < e + n) {
        int v = i - e;                  // self loop
        int p = atomicAdd(&cursor[v], 1);
        csr_src[p] = v;
    }
}

// ---------------- fp32 GEMM: C0 = A@W0, C1 = A@W1 (blockIdx.z picks) ----------------
// A [M,K] row-major, W [K,Nout] row-major. 64x64 tile, 4x4 per thread.

__global__ __launch_bounds__(256) void k_gemm2(
        const float* __restrict__ A,
        const float* __restrict__ W0, const float* __restrict__ W1,
        float* __restrict__ C0, float* __restrict__ C1,
        int M, int K, int Nout) {
    const float* W = blockIdx.z ? W1 : W0;
    float* Cd = blockIdx.z ? C1 : C0;
    __shared__ float As[16][68];
    __shared__ float Bs[16][68];
    int tid = threadIdx.x;
    int rowBase = blockIdx.x * 64;
    int colBase = blockIdx.y * 64;
    int tx = tid & 15, ty = tid >> 4;
    float acc[4][4] = {};
    for (int k0 = 0; k0 < K; k0 += 16) {
        #pragma unroll
        for (int i = 0; i < 4; ++i) {
            int l = tid + i * 256;
            int kk = l & 15, m = l >> 4;
            int r = rowBase + m;
            As[kk][m] = (r < M) ? A[(size_t)r * K + k0 + kk] : 0.f;
        }
        #pragma unroll
        for (int i = 0; i < 4; ++i) {
            int l = tid + i * 256;
            int nn = l & 63, kk = l >> 6;
            Bs[kk][nn] = W[(size_t)(k0 + kk) * Nout + colBase + nn];
        }
        __syncthreads();
        #pragma unroll
        for (int kk = 0; kk < 16; ++kk) {
            float4 a4 = *(const float4*)&As[kk][ty * 4];
            float4 b4 = *(const float4*)&Bs[kk][tx * 4];
            float av[4] = {a4.x, a4.y, a4.z, a4.w};
            float bv[4] = {b4.x, b4.y, b4.z, b4.w};
            #pragma unroll
            for (int i = 0; i < 4; ++i)
                #pragma unroll
                for (int j = 0; j < 4; ++j)
                    acc[i][j] = fmaf(av[i], bv[j], acc[i][j]);
        }
        __syncthreads();
    }
    #pragma unroll
    for (int i = 0; i < 4; ++i) {
        int r = rowBase + ty * 4 + i;
        if (r < M) {
            #pragma unroll
            for (int j = 0; j < 4; ++j)
                Cd[(size_t)r * Nout + colBase + tx * 4 + j] = acc[i][j];
        }
    }
}

// ---------------- edge pass: one wave per node, float4 per lane ----------------
// lane l = h*8+q holds channels (h, q*4 .. q*4+3); one edge = one wave-wide
// float4 gather (1 KB). Head dot = 4 in-lane fmas + 3 xor-shuffles over the
// 8 lanes of the head. No online max (logits are O(1); exp can't overflow).

__device__ __forceinline__ float edge_w(float4 x, float4 xr, float4 att) {
    float ex = x.x + xr.x; ex = ex > 0.f ? ex : SLOPE * ex;
    float ey = x.y + xr.y; ey = ey > 0.f ? ey : SLOPE * ey;
    float ez = x.z + xr.z; ez = ez > 0.f ? ez : SLOPE * ez;
    float ew = x.w + xr.w; ew = ew > 0.f ? ew : SLOPE * ew;
    float p = ex * att.x;
    p = fmaf(ey, att.y, p);
    p = fmaf(ez, att.z, p);
    p = fmaf(ew, att.w, p);
    p += __shfl_xor(p, 1);
    p += __shfl_xor(p, 2);
    p += __shfl_xor(p, 4);
    return __expf(p);
}

// returns softmax-weighted value sum (acc/S) for this lane's 4 channels
__device__ __forceinline__ float4 edge_accum(
        const float4* __restrict__ xl4, float4 xr_v, float4 att_v,
        const int* __restrict__ csr_src, int beg, int end, int lane) {
    float4 acc = {0.f, 0.f, 0.f, 0.f};
    float S = 0.f;
    int j = beg;
    for (; j + 4 <= end; j += 4) {
        int s0 = csr_src[j];
        int s1 = csr_src[j + 1];
        int s2 = csr_src[j + 2];
        int s3 = csr_src[j + 3];
        float4 x0 = xl4[(size_t)s0 * 64 + lane];
        float4 x1 = xl4[(size_t)s1 * 64 + lane];
        float4 x2 = xl4[(size_t)s2 * 64 + lane];
        float4 x3 = xl4[(size_t)s3 * 64 + lane];
        float w0 = edge_w(x0, xr_v, att_v);
        float w1 = edge_w(x1, xr_v, att_v);
        float w2 = edge_w(x2, xr_v, att_v);
        float w3 = edge_w(x3, xr_v, att_v);
        S += (w0 + w1) + (w2 + w3);
        acc.x = fmaf(w0, x0.x, acc.x); acc.y = fmaf(w0, x0.y, acc.y);
        acc.z = fmaf(w0, x0.z, acc.z); acc.w = fmaf(w0, x0.w, acc.w);
        acc.x = fmaf(w1, x1.x, acc.x); acc.y = fmaf(w1, x1.y, acc.y);
        acc.z = fmaf(w1, x1.z, acc.z); acc.w = fmaf(w1, x1.w, acc.w);
        acc.x = fmaf(w2, x2.x, acc.x); acc.y = fmaf(w2, x2.y, acc.y);
        acc.z = fmaf(w2, x2.z, acc.z); acc.w = fmaf(w2, x2.w, acc.w);
        acc.x = fmaf(w3, x3.x, acc.x); acc.y = fmaf(w3, x3.y, acc.y);
        acc.z = fmaf(w3, x3.z, acc.z); acc.w = fmaf(w3, x3.w, acc.w);
    }
    for (; j < end; ++j) {
        int s = csr_src[j];
        float4 xv = xl4[(size_t)s * 64 + lane];
        float w = edge_w(xv, xr_v, att_v);
        S += w;
        acc.x = fmaf(w, xv.x, acc.x); acc.y = fmaf(w, xv.y, acc.y);
        acc.z = fmaf(w, xv.z, acc.z); acc.w = fmaf(w, xv.w, acc.w);
    }
    float inv = 1.f / S;
    acc.x *= inv; acc.y *= inv; acc.z *= inv; acc.w *= inv;
    return acc;
}

// layer 0: concat + bias + BN + ELU. 4 nodes per 256-thread block.
__global__ __launch_bounds__(256) void k_edge0(
        const float* __restrict__ xl, const float* __restrict__ xr,
        const float* __restrict__ att,
        const int* __restrict__ row_ptr, const int* __restrict__ csr_src,
        const float* __restrict__ b0, const float* __restrict__ g0,
        const float* __restrict__ be0, const float* __restrict__ m0,
        const float* __restrict__ v0,
        float* __restrict__ hout) {
    int lane = threadIdx.x & 63;
    int i = blockIdx.x * 4 + (threadIdx.x >> 6);
    const float4* xl4 = (const float4*)xl;
    float4 xr_v = ((const float4*)xr)[(size_t)i * 64 + lane];
    float4 att_v = ((const float4*)att)[lane];
    int beg = row_ptr[i], end = row_ptr[i + 1];
    float4 r = edge_accum(xl4, xr_v, att_v, csr_src, beg, end, lane);
    float4 bb = ((const float4*)b0)[lane];
    float4 gg = ((const float4*)g0)[lane];
    float4 ee = ((const float4*)be0)[lane];
    float4 mm = ((const float4*)m0)[lane];
    float4 vv = ((const float4*)v0)[lane];
    float4 o;
    o.x = (r.x + bb.x - mm.x) * rsqrtf(vv.x + BN_EPS) * gg.x + ee.x;
    o.y = (r.y + bb.y - mm.y) * rsqrtf(vv.y + BN_EPS) * gg.y + ee.y;
    o.z = (r.z + bb.z - mm.z) * rsqrtf(vv.z + BN_EPS) * gg.z + ee.z;
    o.w = (r.w + bb.w - mm.w) * rsqrtf(vv.w + BN_EPS) * gg.w + ee.w;
    o.x = o.x > 0.f ? o.x : expm1f(o.x);
    o.y = o.y > 0.f ? o.y : expm1f(o.y);
    o.z = o.z > 0.f ? o.z : expm1f(o.z);
    o.w = o.w > 0.f ? o.w : expm1f(o.w);
    ((float4*)hout)[(size_t)i * 64 + lane] = o;
}

// layer 1: head-mean + bias + BN + classifier, fully in-register.
__global__ __launch_bounds__(256) void k_edge1(
        const float* __restrict__ xl, const float* __restrict__ xr,
        const float* __restrict__ att,
        const int* __restrict__ row_ptr, const int* __restrict__ csr_src,
        const float* __restrict__ b1, const float* __restrict__ g1,
        const float* __restrict__ be1, const float* __restrict__ m1,
        const float* __restrict__ v1,
        const float* __restrict__ Wc, const float* __restrict__ bc,
        float* __restrict__ out) {
    int lane = threadIdx.x & 63;
    int q = lane & 7;
    int i = blockIdx.x * 4 + (threadIdx.x >> 6);
    const float4* xl4 = (const float4*)xl;
    float4 xr_v = ((const float4*)xr)[(size_t)i * 64 + lane];
    float4 att_v = ((const float4*)att)[lane];
    int beg = row_ptr[i], end = row_ptr[i + 1];
    float4 r = edge_accum(xl4, xr_v, att_v, csr_src, beg, end, lane);
    // head mean: sum over h (lane bits 3,4,5)
    #pragma unroll
    for (int mask = 8; mask <= 32; mask <<= 1) {
        r.x += __shfl_xor(r.x, mask);
        r.y += __shfl_xor(r.y, mask);
        r.z += __shfl_xor(r.z, mask);
        r.w += __shfl_xor(r.w, mask);
    }
    float4 bb = ((const float4*)b1)[q];
    float4 gg = ((const float4*)g1)[q];
    float4 ee = ((const float4*)be1)[q];
    float4 mm = ((const float4*)m1)[q];
    float4 vv = ((const float4*)v1)[q];
    r.x = (r.x * 0.125f + bb.x - mm.x) * rsqrtf(vv.x + BN_EPS) * gg.x + ee.x;
    r.y = (r.y * 0.125f + bb.y - mm.y) * rsqrtf(vv.y + BN_EPS) * gg.y + ee.y;
    r.z = (r.z * 0.125f + bb.z - mm.z) * rsqrtf(vv.z + BN_EPS) * gg.z + ee.z;
    r.w = (r.w * 0.125f + bb.w - mm.w) * rsqrtf(vv.w + BN_EPS) * gg.w + ee.w;
    // classifier: Wc[32,2]; lane holds channels q*4..q*4+3
    float4 wc0 = ((const float4*)Wc)[q * 2];       // Wc[q*4+0][0..1], Wc[q*4+1][0..1]
    float4 wc1 = ((const float4*)Wc)[q * 2 + 1];   // Wc[q*4+2][0..1], Wc[q*4+3][0..1]
    float o0 = r.x * wc0.x + r.y * wc0.z + r.z * wc1.x + r.w * wc1.z;
    float o1 = r.x * wc0.y + r.y * wc0.w + r.z * wc1.y + r.w * wc1.w;
    #pragma unroll
    for (int mask = 1; mask <= 4; mask <<= 1) {
        o0 += __shfl_xor(o0, mask);
        o1 += __shfl_xor(o1, mask);
    }
    if (lane == 0) {
        float2 ov = {o0 + bc[0], o1 + bc[1]};
        *(float2*)(out + (size_t)i * 2) = ov;
    }
}

// ---------------- launcher ----------------

extern "C" void kernel_launch(void* const* d_in, const int* in_sizes, int n_in,
                              void* d_out, int out_size, void* d_ws, size_t ws_size,
                              hipStream_t stream) {
    const float* x    = (const float*)d_in[0];
    const int*   ei   = (const int*)d_in[1];
    const float* Wl0  = (const float*)d_in[2];
    const float* Wr0  = (const float*)d_in[3];
    const float* att0 = (const float*)d_in[4];
    const float* b0   = (const float*)d_in[5];
    const float* g0   = (const float*)d_in[6];
    const float* be0  = (const float*)d_in[7];
    const float* m0   = (const float*)d_in[8];
    const float* v0   = (const float*)d_in[9];
    const float* Wl1  = (const float*)d_in[10];
    const float* Wr1  = (const float*)d_in[11];
    const float* att1 = (const float*)d_in[12];
    const float* b1   = (const float*)d_in[13];
    const float* g1   = (const float*)d_in[14];
    const float* be1  = (const float*)d_in[15];
    const float* m1   = (const float*)d_in[16];
    const float* v1   = (const float*)d_in[17];
    const float* Wc   = (const float*)d_in[18];
    const float* bc   = (const float*)d_in[19];
    float* out = (float*)d_out;

    const int N = N_NODES, E = E_EDGES;
    const int* srcp = ei;        // edge_index[0]
    const int* dstp = ei + E;    // edge_index[1]

    float* bufA = (float*)d_ws;                       // xl   [N,256]
    float* bufB = bufA + (size_t)N * HC;              // xr   [N,256]
    float* bufC = bufB + (size_t)N * HC;              // h0   [N,256]
    int* deg     = (int*)(bufC + (size_t)N * HC);
    int* row_ptr = deg + N;
    int* cursor  = row_ptr + (N + 1);
    int* csr_src = cursor + N;                        // E+N entries

    // CSR build (by dst)
    k_init_deg<<<(N + 255) / 256, 256, 0, stream>>>(deg, N);
    k_hist<<<(E + 255) / 256, 256, 0, stream>>>(dstp, deg, E);
    k_scan<<<1, 1024, 0, stream>>>(deg, row_ptr, cursor, N);
    k_fill<<<(E + N + 255) / 256, 256, 0, stream>>>(srcp, dstp, cursor, csr_src, E, N);

    dim3 ggrid((N + 63) / 64, HC / 64, 2);
    // layer 0 projections: xl0 = x@Wl0, xr0 = x@Wr0
    k_gemm2<<<ggrid, 256, 0, stream>>>(x, Wl0, Wr0, bufA, bufB, N, IN_CH, HC);
    // layer 0 edge pass + BN + ELU -> bufC
    k_edge0<<<N / 4, 256, 0, stream>>>(bufA, bufB, att0, row_ptr, csr_src,
                                       b0, g0, be0, m0, v0, bufC);
    // layer 1 projections: xl1 = h0@Wl1, xr1 = h0@Wr1
    k_gemm2<<<ggrid, 256, 0, stream>>>(bufC, Wl1, Wr1, bufA, bufB, N, HC, HC);
    // layer 1 edge pass + head-mean + BN + classifier -> out
    k_edge1<<<N / 4, 256, 0, stream>>>(bufA, bufB, att1, row_ptr, csr_src,
                                       b1, g1, be1, m1, v1, Wc, bc, out);
}

// Round 4
// 674.639 us; speedup vs baseline: 1.7008x; 1.2094x over previous
//
#include <hip/hip_runtime.h>
#include <math.h>

#define N_NODES 50000
#define M_PAD   50048    // 391 * 128
#define E_EDGES 800000
#define IN_CH   128
#define C_CH    32
#define H_HEADS 8
#define HC      256      // H_HEADS * C_CH
#define BN_EPS  1e-5f
#define SLOPE   0.2f

typedef _Float16 f16x8 __attribute__((ext_vector_type(8)));
typedef _Float16 f16x4 __attribute__((ext_vector_type(4)));
typedef float    f32x4 __attribute__((ext_vector_type(4)));

// ---------------- CSR build ----------------

__global__ void k_init_deg(int* deg, int n) {
    int i = blockIdx.x * blockDim.x + threadIdx.x;
    if (i < n) deg[i] = 1;              // self-loop contributes 1
}

__global__ void k_hist(const int* __restrict__ dst, int* deg, int e) {
    int i = blockIdx.x * blockDim.x + threadIdx.x;
    if (i < e) atomicAdd(&deg[dst[i]], 1);
}

__global__ void k_scan(const int* __restrict__ deg, int* row_ptr, int* cursor, int n) {
    __shared__ int part[1024];
    int tid = threadIdx.x;
    int per = (n + 1023) >> 10;
    int start = tid * per;
    int end = min(start + per, n);
    int s = 0;
    for (int i = start; i < end; ++i) s += deg[i];
    part[tid] = s;
    __syncthreads();
    for (int off = 1; off < 1024; off <<= 1) {
        int u = 0;
        if (tid >= off) u = part[tid - off];
        __syncthreads();
        part[tid] += u;
        __syncthreads();
    }
    int run = part[tid] - s;            // exclusive prefix for this chunk
    for (int i = start; i < end; ++i) {
        row_ptr[i] = run;
        cursor[i] = run;
        run += deg[i];
    }
    if (tid == 1023) row_ptr[n] = part[1023];
}

__global__ void k_fill(const int* __restrict__ src, const int* __restrict__ dst,
                       int* cursor, int* csr_src, int e, int n) {
    int i = blockIdx.x * blockDim.x + threadIdx.x;
    if (i < e) {
        int d = dst[i];
        int p = atomicAdd(&cursor[d], 1);
        csr_src[p] = src[i];
    } else if (i < e + n) {
        int v = i - e;                  // self loop
        int p = atomicAdd(&cursor[v], 1);
        csr_src[p] = v;
    }
}

// ---------------- fp32 -> f16 hi/lo split kernels ----------------

// x [N_NODES,128] -> x_hi/x_lo [M_PAD,128] (pad rows zeroed)
__global__ void k_split_x(const float* __restrict__ x,
                          _Float16* __restrict__ xh, _Float16* __restrict__ xlo) {
    int t = blockIdx.x * blockDim.x + threadIdx.x;   // one float4 per thread
    if (t >= M_PAD * (IN_CH / 4)) return;
    int row = t / (IN_CH / 4);
    float4 v = {0.f, 0.f, 0.f, 0.f};
    if (row < N_NODES) v = ((const float4*)x)[t];
    f16x4 h = { (_Float16)v.x, (_Float16)v.y, (_Float16)v.z, (_Float16)v.w };
    f16x4 l = { (_Float16)(v.x - (float)h.x), (_Float16)(v.y - (float)h.y),
                (_Float16)(v.z - (float)h.z), (_Float16)(v.w - (float)h.w) };
    ((f16x4*)xh)[t] = h;
    ((f16x4*)xlo)[t] = l;
}

// W [K,N] -> Wt_hi/Wt_lo [N,K] (transposed, k-contiguous)
__global__ void k_split_w(const float* __restrict__ W,
                          _Float16* __restrict__ wh, _Float16* __restrict__ wl,
                          int K, int N) {
    int t = blockIdx.x * blockDim.x + threadIdx.x;
    if (t >= K * N) return;
    int n = t / K, k = t - n * K;
    float v = W[(size_t)k * N + n];
    _Float16 h = (_Float16)v;
    wh[t] = h;
    wl[t] = (_Float16)(v - (float)h);
}

// ---------------- f16-split MFMA GEMM ----------------
// C[M_PAD,256] = A[M_PAD,K] @ W[K,256], A given as hi/lo f16, W as transposed
// hi/lo f16 [256][K]. 3-term split: Ah*Bh + Ah*Bl + Al*Bh (lo*lo dropped,
// ~2^-22 relative -- negligible). blockIdx.z picks (W0,C0) vs (W1,C1).
// Tile: BM=128, BN=128, BK=32; 4 waves; wave w owns rows [w*32,w*32+32).
// mfma_f32_16x16x32_f16 layouts (m89/m91-verified):
//   A: m=lane&15, k=(lane>>4)*8+j   B: n=lane&15, k=(lane>>4)*8+j
//   C/D: col=lane&15, row=(lane>>4)*4+reg

#define BK  32
#define LDA 40   // LDS row pitch in f16 (32 + 8 pad -> 80 B, 16B-aligned)

__global__ __launch_bounds__(256) void k_gemm_mfma(
        const _Float16* __restrict__ A_hi, const _Float16* __restrict__ A_lo,
        const _Float16* __restrict__ W0h, const _Float16* __restrict__ W0l,
        const _Float16* __restrict__ W1h, const _Float16* __restrict__ W1l,
        float* __restrict__ C0, float* __restrict__ C1, int K) {
    const _Float16* Wh = blockIdx.z ? W1h : W0h;
    const _Float16* Wl = blockIdx.z ? W1l : W0l;
    float* C = blockIdx.z ? C1 : C0;
    __shared__ _Float16 Ah[128 * LDA], Al[128 * LDA];
    __shared__ _Float16 Bh[128 * LDA], Bl[128 * LDA];
    int t = threadIdx.x;
    int lane = t & 63, wv = t >> 6;
    int quad = lane >> 4, r16 = lane & 15;
    size_t mBase = (size_t)blockIdx.x * 128;
    size_t nBase = (size_t)blockIdx.y * 128;
    int sr = t >> 2;              // staging row 0..63
    int sc = (t & 3) * 8;         // staging col (f16 units)
    f32x4 acc[2][8] = {};
    for (int k0 = 0; k0 < K; k0 += BK) {
        const _Float16* gAh = A_hi + (mBase + sr) * K + k0 + sc;
        const _Float16* gAl = A_lo + (mBase + sr) * K + k0 + sc;
        const _Float16* gBh = Wh + (nBase + sr) * K + k0 + sc;
        const _Float16* gBl = Wl + (nBase + sr) * K + k0 + sc;
        *(f16x8*)&Ah[sr * LDA + sc]        = *(const f16x8*)gAh;
        *(f16x8*)&Ah[(sr + 64) * LDA + sc] = *(const f16x8*)(gAh + (size_t)64 * K);
        *(f16x8*)&Al[sr * LDA + sc]        = *(const f16x8*)gAl;
        *(f16x8*)&Al[(sr + 64) * LDA + sc] = *(const f16x8*)(gAl + (size_t)64 * K);
        *(f16x8*)&Bh[sr * LDA + sc]        = *(const f16x8*)gBh;
        *(f16x8*)&Bh[(sr + 64) * LDA + sc] = *(const f16x8*)(gBh + (size_t)64 * K);
        *(f16x8*)&Bl[sr * LDA + sc]        = *(const f16x8*)gBl;
        *(f16x8*)&Bl[(sr + 64) * LDA + sc] = *(const f16x8*)(gBl + (size_t)64 * K);
        __syncthreads();
        f16x8 ah[2], al[2];
        #pragma unroll
        for (int mi = 0; mi < 2; ++mi) {
            int m = wv * 32 + mi * 16 + r16;
            ah[mi] = *(f16x8*)&Ah[m * LDA + quad * 8];
            al[mi] = *(f16x8*)&Al[m * LDA + quad * 8];
        }
        #pragma unroll
        for (int ni = 0; ni < 8; ++ni) {
            int n = ni * 16 + r16;
            f16x8 bhv = *(f16x8*)&Bh[n * LDA + quad * 8];
            f16x8 blv = *(f16x8*)&Bl[n * LDA + quad * 8];
            #pragma unroll
            for (int mi = 0; mi < 2; ++mi) {
                acc[mi][ni] = __builtin_amdgcn_mfma_f32_16x16x32_f16(ah[mi], bhv, acc[mi][ni], 0, 0, 0);
                acc[mi][ni] = __builtin_amdgcn_mfma_f32_16x16x32_f16(ah[mi], blv, acc[mi][ni], 0, 0, 0);
                acc[mi][ni] = __builtin_amdgcn_mfma_f32_16x16x32_f16(al[mi], bhv, acc[mi][ni], 0, 0, 0);
            }
        }
        __syncthreads();
    }
    #pragma unroll
    for (int mi = 0; mi < 2; ++mi) {
        #pragma unroll
        for (int r = 0; r < 4; ++r) {
            size_t row = mBase + wv * 32 + mi * 16 + quad * 4 + r;
            float* cp = C + row * 256 + nBase + r16;
            #pragma unroll
            for (int ni = 0; ni < 8; ++ni)
                cp[ni * 16] = acc[mi][ni][r];
        }
    }
}

// ---------------- edge pass: one wave per node, float4 per lane ----------------

__device__ __forceinline__ float edge_w(float4 x, float4 xr, float4 att) {
    float ex = x.x + xr.x; ex = ex > 0.f ? ex : SLOPE * ex;
    float ey = x.y + xr.y; ey = ey > 0.f ? ey : SLOPE * ey;
    float ez = x.z + xr.z; ez = ez > 0.f ? ez : SLOPE * ez;
    float ew = x.w + xr.w; ew = ew > 0.f ? ew : SLOPE * ew;
    float p = ex * att.x;
    p = fmaf(ey, att.y, p);
    p = fmaf(ez, att.z, p);
    p = fmaf(ew, att.w, p);
    p += __shfl_xor(p, 1);
    p += __shfl_xor(p, 2);
    p += __shfl_xor(p, 4);
    return __expf(p);
}

__device__ __forceinline__ float4 edge_accum(
        const float4* __restrict__ xl4, float4 xr_v, float4 att_v,
        const int* __restrict__ csr_src, int beg, int end, int lane) {
    float4 acc = {0.f, 0.f, 0.f, 0.f};
    float S = 0.f;
    int j = beg;
    for (; j + 4 <= end; j += 4) {
        int s0 = csr_src[j];
        int s1 = csr_src[j + 1];
        int s2 = csr_src[j + 2];
        int s3 = csr_src[j + 3];
        float4 x0 = xl4[(size_t)s0 * 64 + lane];
        float4 x1 = xl4[(size_t)s1 * 64 + lane];
        float4 x2 = xl4[(size_t)s2 * 64 + lane];
        float4 x3 = xl4[(size_t)s3 * 64 + lane];
        float w0 = edge_w(x0, xr_v, att_v);
        float w1 = edge_w(x1, xr_v, att_v);
        float w2 = edge_w(x2, xr_v, att_v);
        float w3 = edge_w(x3, xr_v, att_v);
        S += (w0 + w1) + (w2 + w3);
        acc.x = fmaf(w0, x0.x, acc.x); acc.y = fmaf(w0, x0.y, acc.y);
        acc.z = fmaf(w0, x0.z, acc.z); acc.w = fmaf(w0, x0.w, acc.w);
        acc.x = fmaf(w1, x1.x, acc.x); acc.y = fmaf(w1, x1.y, acc.y);
        acc.z = fmaf(w1, x1.z, acc.z); acc.w = fmaf(w1, x1.w, acc.w);
        acc.x = fmaf(w2, x2.x, acc.x); acc.y = fmaf(w2, x2.y, acc.y);
        acc.z = fmaf(w2, x2.z, acc.z); acc.w = fmaf(w2, x2.w, acc.w);
        acc.x = fmaf(w3, x3.x, acc.x); acc.y = fmaf(w3, x3.y, acc.y);
        acc.z = fmaf(w3, x3.z, acc.z); acc.w = fmaf(w3, x3.w, acc.w);
    }
    for (; j < end; ++j) {
        int s = csr_src[j];
        float4 xv = xl4[(size_t)s * 64 + lane];
        float w = edge_w(xv, xr_v, att_v);
        S += w;
        acc.x = fmaf(w, xv.x, acc.x); acc.y = fmaf(w, xv.y, acc.y);
        acc.z = fmaf(w, xv.z, acc.z); acc.w = fmaf(w, xv.w, acc.w);
    }
    float inv = 1.f / S;
    acc.x *= inv; acc.y *= inv; acc.z *= inv; acc.w *= inv;
    return acc;
}

// layer 0: concat + bias + BN + ELU -> h0 written as f16 hi/lo split.
__global__ __launch_bounds__(256) void k_edge0(
        const float* __restrict__ xl, const float* __restrict__ xr,
        const float* __restrict__ att,
        const int* __restrict__ row_ptr, const int* __restrict__ csr_src,
        const float* __restrict__ b0, const float* __restrict__ g0,
        const float* __restrict__ be0, const float* __restrict__ m0,
        const float* __restrict__ v0,
        _Float16* __restrict__ h0h, _Float16* __restrict__ h0l) {
    int lane = threadIdx.x & 63;
    int i = blockIdx.x * 4 + (threadIdx.x >> 6);
    const float4* xl4 = (const float4*)xl;
    float4 xr_v = ((const float4*)xr)[(size_t)i * 64 + lane];
    float4 att_v = ((const float4*)att)[lane];
    int beg = row_ptr[i], end = row_ptr[i + 1];
    float4 r = edge_accum(xl4, xr_v, att_v, csr_src, beg, end, lane);
    float4 bb = ((const float4*)b0)[lane];
    float4 gg = ((const float4*)g0)[lane];
    float4 ee = ((const float4*)be0)[lane];
    float4 mm = ((const float4*)m0)[lane];
    float4 vv = ((const float4*)v0)[lane];
    float4 o;
    o.x = (r.x + bb.x - mm.x) * rsqrtf(vv.x + BN_EPS) * gg.x + ee.x;
    o.y = (r.y + bb.y - mm.y) * rsqrtf(vv.y + BN_EPS) * gg.y + ee.y;
    o.z = (r.z + bb.z - mm.z) * rsqrtf(vv.z + BN_EPS) * gg.z + ee.z;
    o.w = (r.w + bb.w - mm.w) * rsqrtf(vv.w + BN_EPS) * gg.w + ee.w;
    o.x = o.x > 0.f ? o.x : expm1f(o.x);
    o.y = o.y > 0.f ? o.y : expm1f(o.y);
    o.z = o.z > 0.f ? o.z : expm1f(o.z);
    o.w = o.w > 0.f ? o.w : expm1f(o.w);
    f16x4 hh = { (_Float16)o.x, (_Float16)o.y, (_Float16)o.z, (_Float16)o.w };
    f16x4 hl = { (_Float16)(o.x - (float)hh.x), (_Float16)(o.y - (float)hh.y),
                 (_Float16)(o.z - (float)hh.z), (_Float16)(o.w - (float)hh.w) };
    ((f16x4*)h0h)[(size_t)i * 64 + lane] = hh;
    ((f16x4*)h0l)[(size_t)i * 64 + lane] = hl;
}

// layer 1: head-mean + bias + BN + classifier, fully in-register.
__global__ __launch_bounds__(256) void k_edge1(
        const float* __restrict__ xl, const float* __restrict__ xr,
        const float* __restrict__ att,
        const int* __restrict__ row_ptr, const int* __restrict__ csr_src,
        const float* __restrict__ b1, const float* __restrict__ g1,
        const float* __restrict__ be1, const float* __restrict__ m1,
        const float* __restrict__ v1,
        const float* __restrict__ Wc, const float* __restrict__ bc,
        float* __restrict__ out) {
    int lane = threadIdx.x & 63;
    int q = lane & 7;
    int i = blockIdx.x * 4 + (threadIdx.x >> 6);
    const float4* xl4 = (const float4*)xl;
    float4 xr_v = ((const float4*)xr)[(size_t)i * 64 + lane];
    float4 att_v = ((const float4*)att)[lane];
    int beg = row_ptr[i], end = row_ptr[i + 1];
    float4 r = edge_accum(xl4, xr_v, att_v, csr_src, beg, end, lane);
    #pragma unroll
    for (int mask = 8; mask <= 32; mask <<= 1) {
        r.x += __shfl_xor(r.x, mask);
        r.y += __shfl_xor(r.y, mask);
        r.z += __shfl_xor(r.z, mask);
        r.w += __shfl_xor(r.w, mask);
    }
    float4 bb = ((const float4*)b1)[q];
    float4 gg = ((const float4*)g1)[q];
    float4 ee = ((const float4*)be1)[q];
    float4 mm = ((const float4*)m1)[q];
    float4 vv = ((const float4*)v1)[q];
    r.x = (r.x * 0.125f + bb.x - mm.x) * rsqrtf(vv.x + BN_EPS) * gg.x + ee.x;
    r.y = (r.y * 0.125f + bb.y - mm.y) * rsqrtf(vv.y + BN_EPS) * gg.y + ee.y;
    r.z = (r.z * 0.125f + bb.z - mm.z) * rsqrtf(vv.z + BN_EPS) * gg.z + ee.z;
    r.w = (r.w * 0.125f + bb.w - mm.w) * rsqrtf(vv.w + BN_EPS) * gg.w + ee.w;
    float4 wc0 = ((const float4*)Wc)[q * 2];
    float4 wc1 = ((const float4*)Wc)[q * 2 + 1];
    float o0 = r.x * wc0.x + r.y * wc0.z + r.z * wc1.x + r.w * wc1.z;
    float o1 = r.x * wc0.y + r.y * wc0.w + r.z * wc1.y + r.w * wc1.w;
    #pragma unroll
    for (int mask = 1; mask <= 4; mask <<= 1) {
        o0 += __shfl_xor(o0, mask);
        o1 += __shfl_xor(o1, mask);
    }
    if (lane == 0) {
        float2 ov = {o0 + bc[0], o1 + bc[1]};
        *(float2*)(out + (size_t)i * 2) = ov;
    }
}

// ---------------- launcher ----------------

extern "C" void kernel_launch(void* const* d_in, const int* in_sizes, int n_in,
                              void* d_out, int out_size, void* d_ws, size_t ws_size,
                              hipStream_t stream) {
    const float* x    = (const float*)d_in[0];
    const int*   ei   = (const int*)d_in[1];
    const float* Wl0  = (const float*)d_in[2];
    const float* Wr0  = (const float*)d_in[3];
    const float* att0 = (const float*)d_in[4];
    const float* b0   = (const float*)d_in[5];
    const float* g0   = (const float*)d_in[6];
    const float* be0  = (const float*)d_in[7];
    const float* m0   = (const float*)d_in[8];
    const float* v0   = (const float*)d_in[9];
    const float* Wl1  = (const float*)d_in[10];
    const float* Wr1  = (const float*)d_in[11];
    const float* att1 = (const float*)d_in[12];
    const float* b1   = (const float*)d_in[13];
    const float* g1   = (const float*)d_in[14];
    const float* be1  = (const float*)d_in[15];
    const float* m1   = (const float*)d_in[16];
    const float* v1   = (const float*)d_in[17];
    const float* Wc   = (const float*)d_in[18];
    const float* bc   = (const float*)d_in[19];
    float* out = (float*)d_out;

    const int N = N_NODES, E = E_EDGES;
    const int* srcp = ei;        // edge_index[0]
    const int* dstp = ei + E;    // edge_index[1]

    // workspace carve-up (16B-aligned chunks)
    char* p = (char*)d_ws;
    float* bufA = (float*)p; p += (size_t)M_PAD * HC * 4;      // xl [M_PAD,256] f32
    float* bufB = (float*)p; p += (size_t)M_PAD * HC * 4;      // xr [M_PAD,256] f32
    // shared region: h0 hi/lo (each M_PAD*256 f16) aliases x hi/lo (each M_PAD*128 f16)
    char* shared0 = p; p += (size_t)M_PAD * HC * 2 * 2;
    _Float16* h0h = (_Float16*)shared0;
    _Float16* h0l = (_Float16*)(shared0 + (size_t)M_PAD * HC * 2);
    _Float16* xh  = (_Float16*)shared0;                        // alias (dead before h0 written)
    _Float16* xlo = (_Float16*)(shared0 + (size_t)M_PAD * IN_CH * 2);
    _Float16* W0lh = (_Float16*)p; p += (size_t)HC * IN_CH * 2;  // Wt of Wl0 [256][128]
    _Float16* W0ll = (_Float16*)p; p += (size_t)HC * IN_CH * 2;
    _Float16* W0rh = (_Float16*)p; p += (size_t)HC * IN_CH * 2;
    _Float16* W0rl = (_Float16*)p; p += (size_t)HC * IN_CH * 2;
    _Float16* W1lh = (_Float16*)p; p += (size_t)HC * HC * 2;     // Wt of Wl1 [256][256]
    _Float16* W1ll = (_Float16*)p; p += (size_t)HC * HC * 2;
    _Float16* W1rh = (_Float16*)p; p += (size_t)HC * HC * 2;
    _Float16* W1rl = (_Float16*)p; p += (size_t)HC * HC * 2;
    int* deg     = (int*)p;
    int* row_ptr = deg + N;
    int* cursor  = row_ptr + (N + 1);
    int* csr_src = cursor + N;                        // E+N entries

    // CSR build (by dst)
    k_init_deg<<<(N + 255) / 256, 256, 0, stream>>>(deg, N);
    k_hist<<<(E + 255) / 256, 256, 0, stream>>>(dstp, deg, E);
    k_scan<<<1, 1024, 0, stream>>>(deg, row_ptr, cursor, N);
    k_fill<<<(E + N + 255) / 256, 256, 0, stream>>>(srcp, dstp, cursor, csr_src, E, N);

    // splits
    k_split_x<<<(M_PAD * (IN_CH / 4) + 255) / 256, 256, 0, stream>>>(x, xh, xlo);
    k_split_w<<<(IN_CH * HC + 255) / 256, 256, 0, stream>>>(Wl0, W0lh, W0ll, IN_CH, HC);
    k_split_w<<<(IN_CH * HC + 255) / 256, 256, 0, stream>>>(Wr0, W0rh, W0rl, IN_CH, HC);
    k_split_w<<<(HC * HC + 255) / 256, 256, 0, stream>>>(Wl1, W1lh, W1ll, HC, HC);
    k_split_w<<<(HC * HC + 255) / 256, 256, 0, stream>>>(Wr1, W1rh, W1rl, HC, HC);

    dim3 ggrid(M_PAD / 128, 2, 2);
    // layer 0 projections: xl0 = x@Wl0, xr0 = x@Wr0  (f16-split MFMA)
    k_gemm_mfma<<<ggrid, 256, 0, stream>>>(xh, xlo, W0lh, W0ll, W0rh, W0rl,
                                           bufA, bufB, IN_CH);
    // layer 0 edge pass + BN + ELU -> h0 (f16 hi/lo)
    k_edge0<<<N / 4, 256, 0, stream>>>(bufA, bufB, att0, row_ptr, csr_src,
                                       b0, g0, be0, m0, v0, h0h, h0l);
    // layer 1 projections: xl1 = h0@Wl1, xr1 = h0@Wr1
    k_gemm_mfma<<<ggrid, 256, 0, stream>>>(h0h, h0l, W1lh, W1ll, W1rh, W1rl,
                                           bufA, bufB, HC);
    // layer 1 edge pass + head-mean + BN + classifier -> out
    k_edge1<<<N / 4, 256, 0, stream>>>(bufA, bufB, att1, row_ptr, csr_src,
                                       b1, g1, be1, m1, v1, Wc, bc, out);
}

// Round 5
// 566.970 us; speedup vs baseline: 2.0237x; 1.1899x over previous
//
#include <hip/hip_runtime.h>
#include <math.h>

#define N_NODES 50000
#define M_PAD   50048    // 391 * 128
#define E_EDGES 800000
#define IN_CH   128
#define C_CH    32
#define H_HEADS 8
#define HC      256      // H_HEADS * C_CH
#define BN_EPS  1e-5f
#define SLOPE   0.2f

typedef _Float16 f16x8 __attribute__((ext_vector_type(8)));
typedef _Float16 f16x4 __attribute__((ext_vector_type(4)));
typedef float    f32x4 __attribute__((ext_vector_type(4)));

// ---------------- CSR build ----------------

__global__ void k_init_deg(int* deg, int n) {
    int i = blockIdx.x * blockDim.x + threadIdx.x;
    if (i < n) deg[i] = 1;              // self-loop contributes 1
}

__global__ void k_hist(const int* __restrict__ dst, int* deg, int e) {
    int i = blockIdx.x * blockDim.x + threadIdx.x;
    if (i < e) atomicAdd(&deg[dst[i]], 1);
}

__global__ void k_scan(const int* __restrict__ deg, int* row_ptr, int* cursor, int n) {
    __shared__ int part[1024];
    int tid = threadIdx.x;
    int per = (n + 1023) >> 10;
    int start = tid * per;
    int end = min(start + per, n);
    int s = 0;
    for (int i = start; i < end; ++i) s += deg[i];
    part[tid] = s;
    __syncthreads();
    for (int off = 1; off < 1024; off <<= 1) {
        int u = 0;
        if (tid >= off) u = part[tid - off];
        __syncthreads();
        part[tid] += u;
        __syncthreads();
    }
    int run = part[tid] - s;            // exclusive prefix for this chunk
    for (int i = start; i < end; ++i) {
        row_ptr[i] = run;
        cursor[i] = run;
        run += deg[i];
    }
    if (tid == 1023) row_ptr[n] = part[1023];
}

__global__ void k_fill(const int* __restrict__ src, const int* __restrict__ dst,
                       int* cursor, int* csr_src, int e, int n) {
    int i = blockIdx.x * blockDim.x + threadIdx.x;
    if (i < e) {
        int d = dst[i];
        int p = atomicAdd(&cursor[d], 1);
        csr_src[p] = src[i];
    } else if (i < e + n) {
        int v = i - e;                  // self loop
        int p = atomicAdd(&cursor[v], 1);
        csr_src[p] = v;
    }
}

// ---------------- fp32 -> f16 hi/lo split kernels ----------------

// x [N_NODES,128] -> x_hi/x_lo [M_PAD,128] (pad rows zeroed)
__global__ void k_split_x(const float* __restrict__ x,
                          _Float16* __restrict__ xh, _Float16* __restrict__ xlo) {
    int t = blockIdx.x * blockDim.x + threadIdx.x;   // one float4 per thread
    if (t >= M_PAD * (IN_CH / 4)) return;
    int row = t / (IN_CH / 4);
    float4 v = {0.f, 0.f, 0.f, 0.f};
    if (row < N_NODES) v = ((const float4*)x)[t];
    f16x4 h = { (_Float16)v.x, (_Float16)v.y, (_Float16)v.z, (_Float16)v.w };
    f16x4 l = { (_Float16)(v.x - (float)h[0]), (_Float16)(v.y - (float)h[1]),
                (_Float16)(v.z - (float)h[2]), (_Float16)(v.w - (float)h[3]) };
    ((f16x4*)xh)[t] = h;
    ((f16x4*)xlo)[t] = l;
}

// W [K,N] -> Wt_hi/Wt_lo [N,K] (transposed, k-contiguous)
__global__ void k_split_w(const float* __restrict__ W,
                          _Float16* __restrict__ wh, _Float16* __restrict__ wl,
                          int K, int N) {
    int t = blockIdx.x * blockDim.x + threadIdx.x;
    if (t >= K * N) return;
    int n = t / K, k = t - n * K;
    float v = W[(size_t)k * N + n];
    _Float16 h = (_Float16)v;
    wh[t] = h;
    wl[t] = (_Float16)(v - (float)h);
}

// ---------------- f16-split MFMA GEMM ----------------
// z=0: C = A@W0 -> Cf16 (the gathered xl side, f16 is enough for softmax
//      logits + messages); z=1: C = A@W1 -> Cf32 (xr side, full precision).
// 3-term split: Ah*Bh + Ah*Bl + Al*Bh (lo*lo dropped, ~2^-22 relative).
// Tile: BM=128, BN=128, BK=32; 4 waves; wave w owns rows [w*32,w*32+32).
// mfma_f32_16x16x32_f16 layouts (m89/m91-verified):
//   A: m=lane&15, k=(lane>>4)*8+j   B: n=lane&15, k=(lane>>4)*8+j
//   C/D: col=lane&15, row=(lane>>4)*4+reg

#define BK  32
#define LDA 40   // LDS row pitch in f16 (32 + 8 pad -> 80 B, 16B-aligned)

__global__ __launch_bounds__(256) void k_gemm_mfma(
        const _Float16* __restrict__ A_hi, const _Float16* __restrict__ A_lo,
        const _Float16* __restrict__ W0h, const _Float16* __restrict__ W0l,
        const _Float16* __restrict__ W1h, const _Float16* __restrict__ W1l,
        _Float16* __restrict__ Cf16, float* __restrict__ Cf32, int K) {
    const _Float16* Wh = blockIdx.z ? W1h : W0h;
    const _Float16* Wl = blockIdx.z ? W1l : W0l;
    __shared__ _Float16 Ah[128 * LDA], Al[128 * LDA];
    __shared__ _Float16 Bh[128 * LDA], Bl[128 * LDA];
    int t = threadIdx.x;
    int lane = t & 63, wv = t >> 6;
    int quad = lane >> 4, r16 = lane & 15;
    size_t mBase = (size_t)blockIdx.x * 128;
    size_t nBase = (size_t)blockIdx.y * 128;
    int sr = t >> 2;              // staging row 0..63
    int sc = (t & 3) * 8;         // staging col (f16 units)
    f32x4 acc[2][8] = {};
    for (int k0 = 0; k0 < K; k0 += BK) {
        const _Float16* gAh = A_hi + (mBase + sr) * K + k0 + sc;
        const _Float16* gAl = A_lo + (mBase + sr) * K + k0 + sc;
        const _Float16* gBh = Wh + (nBase + sr) * K + k0 + sc;
        const _Float16* gBl = Wl + (nBase + sr) * K + k0 + sc;
        *(f16x8*)&Ah[sr * LDA + sc]        = *(const f16x8*)gAh;
        *(f16x8*)&Ah[(sr + 64) * LDA + sc] = *(const f16x8*)(gAh + (size_t)64 * K);
        *(f16x8*)&Al[sr * LDA + sc]        = *(const f16x8*)gAl;
        *(f16x8*)&Al[(sr + 64) * LDA + sc] = *(const f16x8*)(gAl + (size_t)64 * K);
        *(f16x8*)&Bh[sr * LDA + sc]        = *(const f16x8*)gBh;
        *(f16x8*)&Bh[(sr + 64) * LDA + sc] = *(const f16x8*)(gBh + (size_t)64 * K);
        *(f16x8*)&Bl[sr * LDA + sc]        = *(const f16x8*)gBl;
        *(f16x8*)&Bl[(sr + 64) * LDA + sc] = *(const f16x8*)(gBl + (size_t)64 * K);
        __syncthreads();
        f16x8 ah[2], al[2];
        #pragma unroll
        for (int mi = 0; mi < 2; ++mi) {
            int m = wv * 32 + mi * 16 + r16;
            ah[mi] = *(f16x8*)&Ah[m * LDA + quad * 8];
            al[mi] = *(f16x8*)&Al[m * LDA + quad * 8];
        }
        #pragma unroll
        for (int ni = 0; ni < 8; ++ni) {
            int n = ni * 16 + r16;
            f16x8 bhv = *(f16x8*)&Bh[n * LDA + quad * 8];
            f16x8 blv = *(f16x8*)&Bl[n * LDA + quad * 8];
            #pragma unroll
            for (int mi = 0; mi < 2; ++mi) {
                acc[mi][ni] = __builtin_amdgcn_mfma_f32_16x16x32_f16(ah[mi], bhv, acc[mi][ni], 0, 0, 0);
                acc[mi][ni] = __builtin_amdgcn_mfma_f32_16x16x32_f16(ah[mi], blv, acc[mi][ni], 0, 0, 0);
                acc[mi][ni] = __builtin_amdgcn_mfma_f32_16x16x32_f16(al[mi], bhv, acc[mi][ni], 0, 0, 0);
            }
        }
        __syncthreads();
    }
    if (blockIdx.z == 0) {
        #pragma unroll
        for (int mi = 0; mi < 2; ++mi)
            #pragma unroll
            for (int r = 0; r < 4; ++r) {
                size_t row = mBase + wv * 32 + mi * 16 + quad * 4 + r;
                _Float16* cp = Cf16 + row * 256 + nBase + r16;
                #pragma unroll
                for (int ni = 0; ni < 8; ++ni)
                    cp[ni * 16] = (_Float16)acc[mi][ni][r];
            }
    } else {
        #pragma unroll
        for (int mi = 0; mi < 2; ++mi)
            #pragma unroll
            for (int r = 0; r < 4; ++r) {
                size_t row = mBase + wv * 32 + mi * 16 + quad * 4 + r;
                float* cp = Cf32 + row * 256 + nBase + r16;
                #pragma unroll
                for (int ni = 0; ni < 8; ++ni)
                    cp[ni * 16] = acc[mi][ni][r];
            }
    }
}

// ---------------- edge pass: one wave per node, 4 channels per lane ----------------
// xl is stored f16 [node][256]; one edge gather = 8 B/lane (512 B/wave).

__device__ __forceinline__ float edge_w(float4 x, float4 xr, float4 att) {
    float ex = x.x + xr.x; ex = ex > 0.f ? ex : SLOPE * ex;
    float ey = x.y + xr.y; ey = ey > 0.f ? ey : SLOPE * ey;
    float ez = x.z + xr.z; ez = ez > 0.f ? ez : SLOPE * ez;
    float ew = x.w + xr.w; ew = ew > 0.f ? ew : SLOPE * ew;
    float p = ex * att.x;
    p = fmaf(ey, att.y, p);
    p = fmaf(ez, att.z, p);
    p = fmaf(ew, att.w, p);
    p += __shfl_xor(p, 1);
    p += __shfl_xor(p, 2);
    p += __shfl_xor(p, 4);
    return __expf(p);
}

__device__ __forceinline__ float4 cvt4(f16x4 v) {
    float4 r = { (float)v[0], (float)v[1], (float)v[2], (float)v[3] };
    return r;
}

__device__ __forceinline__ float4 edge_accum(
        const f16x4* __restrict__ xl4, float4 xr_v, float4 att_v,
        const int* __restrict__ csr_src, int beg, int end, int lane) {
    float4 acc = {0.f, 0.f, 0.f, 0.f};
    float S = 0.f;
    int j = beg;
    for (; j + 4 <= end; j += 4) {
        int s0 = csr_src[j];
        int s1 = csr_src[j + 1];
        int s2 = csr_src[j + 2];
        int s3 = csr_src[j + 3];
        f16x4 h0 = xl4[(size_t)s0 * 64 + lane];
        f16x4 h1 = xl4[(size_t)s1 * 64 + lane];
        f16x4 h2 = xl4[(size_t)s2 * 64 + lane];
        f16x4 h3 = xl4[(size_t)s3 * 64 + lane];
        float4 x0 = cvt4(h0);
        float4 x1 = cvt4(h1);
        float4 x2 = cvt4(h2);
        float4 x3 = cvt4(h3);
        float w0 = edge_w(x0, xr_v, att_v);
        float w1 = edge_w(x1, xr_v, att_v);
        float w2 = edge_w(x2, xr_v, att_v);
        float w3 = edge_w(x3, xr_v, att_v);
        S += (w0 + w1) + (w2 + w3);
        acc.x = fmaf(w0, x0.x, acc.x); acc.y = fmaf(w0, x0.y, acc.y);
        acc.z = fmaf(w0, x0.z, acc.z); acc.w = fmaf(w0, x0.w, acc.w);
        acc.x = fmaf(w1, x1.x, acc.x); acc.y = fmaf(w1, x1.y, acc.y);
        acc.z = fmaf(w1, x1.z, acc.z); acc.w = fmaf(w1, x1.w, acc.w);
        acc.x = fmaf(w2, x2.x, acc.x); acc.y = fmaf(w2, x2.y, acc.y);
        acc.z = fmaf(w2, x2.z, acc.z); acc.w = fmaf(w2, x2.w, acc.w);
        acc.x = fmaf(w3, x3.x, acc.x); acc.y = fmaf(w3, x3.y, acc.y);
        acc.z = fmaf(w3, x3.z, acc.z); acc.w = fmaf(w3, x3.w, acc.w);
    }
    for (; j < end; ++j) {
        int s = csr_src[j];
        float4 xv = cvt4(xl4[(size_t)s * 64 + lane]);
        float w = edge_w(xv, xr_v, att_v);
        S += w;
        acc.x = fmaf(w, xv.x, acc.x); acc.y = fmaf(w, xv.y, acc.y);
        acc.z = fmaf(w, xv.z, acc.z); acc.w = fmaf(w, xv.w, acc.w);
    }
    float inv = 1.f / S;
    acc.x *= inv; acc.y *= inv; acc.z *= inv; acc.w *= inv;
    return acc;
}

// layer 0: concat + bias + BN + ELU -> h0 written as f16 hi/lo split.
__global__ __launch_bounds__(256) void k_edge0(
        const _Float16* __restrict__ xl, const float* __restrict__ xr,
        const float* __restrict__ att,
        const int* __restrict__ row_ptr, const int* __restrict__ csr_src,
        const float* __restrict__ b0, const float* __restrict__ g0,
        const float* __restrict__ be0, const float* __restrict__ m0,
        const float* __restrict__ v0,
        _Float16* __restrict__ h0h, _Float16* __restrict__ h0l) {
    int lane = threadIdx.x & 63;
    int i = blockIdx.x * 4 + (threadIdx.x >> 6);
    const f16x4* xl4 = (const f16x4*)xl;
    float4 xr_v = ((const float4*)xr)[(size_t)i * 64 + lane];
    float4 att_v = ((const float4*)att)[lane];
    int beg = row_ptr[i], end = row_ptr[i + 1];
    float4 r = edge_accum(xl4, xr_v, att_v, csr_src, beg, end, lane);
    float4 bb = ((const float4*)b0)[lane];
    float4 gg = ((const float4*)g0)[lane];
    float4 ee = ((const float4*)be0)[lane];
    float4 mm = ((const float4*)m0)[lane];
    float4 vv = ((const float4*)v0)[lane];
    float4 o;
    o.x = (r.x + bb.x - mm.x) * rsqrtf(vv.x + BN_EPS) * gg.x + ee.x;
    o.y = (r.y + bb.y - mm.y) * rsqrtf(vv.y + BN_EPS) * gg.y + ee.y;
    o.z = (r.z + bb.z - mm.z) * rsqrtf(vv.z + BN_EPS) * gg.z + ee.z;
    o.w = (r.w + bb.w - mm.w) * rsqrtf(vv.w + BN_EPS) * gg.w + ee.w;
    o.x = o.x > 0.f ? o.x : expm1f(o.x);
    o.y = o.y > 0.f ? o.y : expm1f(o.y);
    o.z = o.z > 0.f ? o.z : expm1f(o.z);
    o.w = o.w > 0.f ? o.w : expm1f(o.w);
    f16x4 hh = { (_Float16)o.x, (_Float16)o.y, (_Float16)o.z, (_Float16)o.w };
    f16x4 hl = { (_Float16)(o.x - (float)hh[0]), (_Float16)(o.y - (float)hh[1]),
                 (_Float16)(o.z - (float)hh[2]), (_Float16)(o.w - (float)hh[3]) };
    ((f16x4*)h0h)[(size_t)i * 64 + lane] = hh;
    ((f16x4*)h0l)[(size_t)i * 64 + lane] = hl;
}

// layer 1: head-mean + bias + BN + classifier, fully in-register.
__global__ __launch_bounds__(256) void k_edge1(
        const _Float16* __restrict__ xl, const float* __restrict__ xr,
        const float* __restrict__ att,
        const int* __restrict__ row_ptr, const int* __restrict__ csr_src,
        const float* __restrict__ b1, const float* __restrict__ g1,
        const float* __restrict__ be1, const float* __restrict__ m1,
        const float* __restrict__ v1,
        const float* __restrict__ Wc, const float* __restrict__ bc,
        float* __restrict__ out) {
    int lane = threadIdx.x & 63;
    int q = lane & 7;
    int i = blockIdx.x * 4 + (threadIdx.x >> 6);
    const f16x4* xl4 = (const f16x4*)xl;
    float4 xr_v = ((const float4*)xr)[(size_t)i * 64 + lane];
    float4 att_v = ((const float4*)att)[lane];
    int beg = row_ptr[i], end = row_ptr[i + 1];
    float4 r = edge_accum(xl4, xr_v, att_v, csr_src, beg, end, lane);
    #pragma unroll
    for (int mask = 8; mask <= 32; mask <<= 1) {
        r.x += __shfl_xor(r.x, mask);
        r.y += __shfl_xor(r.y, mask);
        r.z += __shfl_xor(r.z, mask);
        r.w += __shfl_xor(r.w, mask);
    }
    float4 bb = ((const float4*)b1)[q];
    float4 gg = ((const float4*)g1)[q];
    float4 ee = ((const float4*)be1)[q];
    float4 mm = ((const float4*)m1)[q];
    float4 vv = ((const float4*)v1)[q];
    r.x = (r.x * 0.125f + bb.x - mm.x) * rsqrtf(vv.x + BN_EPS) * gg.x + ee.x;
    r.y = (r.y * 0.125f + bb.y - mm.y) * rsqrtf(vv.y + BN_EPS) * gg.y + ee.y;
    r.z = (r.z * 0.125f + bb.z - mm.z) * rsqrtf(vv.z + BN_EPS) * gg.z + ee.z;
    r.w = (r.w * 0.125f + bb.w - mm.w) * rsqrtf(vv.w + BN_EPS) * gg.w + ee.w;
    float4 wc0 = ((const float4*)Wc)[q * 2];
    float4 wc1 = ((const float4*)Wc)[q * 2 + 1];
    float o0 = r.x * wc0.x + r.y * wc0.z + r.z * wc1.x + r.w * wc1.z;
    float o1 = r.x * wc0.y + r.y * wc0.w + r.z * wc1.y + r.w * wc1.w;
    #pragma unroll
    for (int mask = 1; mask <= 4; mask <<= 1) {
        o0 += __shfl_xor(o0, mask);
        o1 += __shfl_xor(o1, mask);
    }
    if (lane == 0) {
        float2 ov = {o0 + bc[0], o1 + bc[1]};
        *(float2*)(out + (size_t)i * 2) = ov;
    }
}

// ---------------- launcher ----------------

extern "C" void kernel_launch(void* const* d_in, const int* in_sizes, int n_in,
                              void* d_out, int out_size, void* d_ws, size_t ws_size,
                              hipStream_t stream) {
    const float* x    = (const float*)d_in[0];
    const int*   ei   = (const int*)d_in[1];
    const float* Wl0  = (const float*)d_in[2];
    const float* Wr0  = (const float*)d_in[3];
    const float* att0 = (const float*)d_in[4];
    const float* b0   = (const float*)d_in[5];
    const float* g0   = (const float*)d_in[6];
    const float* be0  = (const float*)d_in[7];
    const float* m0   = (const float*)d_in[8];
    const float* v0   = (const float*)d_in[9];
    const float* Wl1  = (const float*)d_in[10];
    const float* Wr1  = (const float*)d_in[11];
    const float* att1 = (const float*)d_in[12];
    const float* b1   = (const float*)d_in[13];
    const float* g1   = (const float*)d_in[14];
    const float* be1  = (const float*)d_in[15];
    const float* m1   = (const float*)d_in[16];
    const float* v1   = (const float*)d_in[17];
    const float* Wc   = (const float*)d_in[18];
    const float* bc   = (const float*)d_in[19];
    float* out = (float*)d_out;

    const int N = N_NODES, E = E_EDGES;
    const int* srcp = ei;        // edge_index[0]
    const int* dstp = ei + E;    // edge_index[1]

    // workspace carve-up (16B-aligned chunks)
    char* p = (char*)d_ws;
    _Float16* xlf = (_Float16*)p; p += (size_t)M_PAD * HC * 2;   // xl [M_PAD,256] f16 (gather table)
    float* bufB   = (float*)p;   p += (size_t)M_PAD * HC * 4;    // xr [M_PAD,256] f32
    // shared region: h0 hi/lo (each M_PAD*256 f16) aliases x hi/lo (each M_PAD*128 f16)
    char* shared0 = p; p += (size_t)M_PAD * HC * 2 * 2;
    _Float16* h0h = (_Float16*)shared0;
    _Float16* h0l = (_Float16*)(shared0 + (size_t)M_PAD * HC * 2);
    _Float16* xh  = (_Float16*)shared0;                          // alias (dead before h0 written)
    _Float16* xlo = (_Float16*)(shared0 + (size_t)M_PAD * IN_CH * 2);
    _Float16* W0lh = (_Float16*)p; p += (size_t)HC * IN_CH * 2;  // Wt of Wl0 [256][128]
    _Float16* W0ll = (_Float16*)p; p += (size_t)HC * IN_CH * 2;
    _Float16* W0rh = (_Float16*)p; p += (size_t)HC * IN_CH * 2;
    _Float16* W0rl = (_Float16*)p; p += (size_t)HC * IN_CH * 2;
    _Float16* W1lh = (_Float16*)p; p += (size_t)HC * HC * 2;     // Wt of Wl1 [256][256]
    _Float16* W1ll = (_Float16*)p; p += (size_t)HC * HC * 2;
    _Float16* W1rh = (_Float16*)p; p += (size_t)HC * HC * 2;
    _Float16* W1rl = (_Float16*)p; p += (size_t)HC * HC * 2;
    int* deg     = (int*)p;
    int* row_ptr = deg + N;
    int* cursor  = row_ptr + (N + 1);
    int* csr_src = cursor + N;                        // E+N entries

    // CSR build (by dst)
    k_init_deg<<<(N + 255) / 256, 256, 0, stream>>>(deg, N);
    k_hist<<<(E + 255) / 256, 256, 0, stream>>>(dstp, deg, E);
    k_scan<<<1, 1024, 0, stream>>>(deg, row_ptr, cursor, N);
    k_fill<<<(E + N + 255) / 256, 256, 0, stream>>>(srcp, dstp, cursor, csr_src, E, N);

    // splits
    k_split_x<<<(M_PAD * (IN_CH / 4) + 255) / 256, 256, 0, stream>>>(x, xh, xlo);
    k_split_w<<<(IN_CH * HC + 255) / 256, 256, 0, stream>>>(Wl0, W0lh, W0ll, IN_CH, HC);
    k_split_w<<<(IN_CH * HC + 255) / 256, 256, 0, stream>>>(Wr0, W0rh, W0rl, IN_CH, HC);
    k_split_w<<<(HC * HC + 255) / 256, 256, 0, stream>>>(Wl1, W1lh, W1ll, HC, HC);
    k_split_w<<<(HC * HC + 255) / 256, 256, 0, stream>>>(Wr1, W1rh, W1rl, HC, HC);

    dim3 ggrid(M_PAD / 128, 2, 2);
    // layer 0 projections: xl0 = x@Wl0 (f16 out), xr0 = x@Wr0 (f32 out)
    k_gemm_mfma<<<ggrid, 256, 0, stream>>>(xh, xlo, W0lh, W0ll, W0rh, W0rl,
                                           xlf, bufB, IN_CH);
    // layer 0 edge pass + BN + ELU -> h0 (f16 hi/lo)
    k_edge0<<<N / 4, 256, 0, stream>>>(xlf, bufB, att0, row_ptr, csr_src,
                                       b0, g0, be0, m0, v0, h0h, h0l);
    // layer 1 projections: xl1 = h0@Wl1 (f16 out), xr1 = h0@Wr1 (f32 out)
    k_gemm_mfma<<<ggrid, 256, 0, stream>>>(h0h, h0l, W1lh, W1ll, W1rh, W1rl,
                                           xlf, bufB, HC);
    // layer 1 edge pass + head-mean + BN + classifier -> out
    k_edge1<<<N / 4, 256, 0, stream>>>(xlf, bufB, att1, row_ptr, csr_src,
                                       b1, g1, be1, m1, v1, Wc, bc, out);
}

// Round 6
// 469.919 us; speedup vs baseline: 2.4417x; 1.2065x over previous
//
#include <hip/hip_runtime.h>
#include <math.h>

#define N_NODES 50000
#define M_PAD   50048    // 391 * 128
#define E_EDGES 800000
#define IN_CH   128
#define C_CH    32
#define H_HEADS 8
#define HC      256      // H_HEADS * C_CH
#define BN_EPS  1e-5f
#define SLOPE   0.2f

#define SCAN_CHUNK 512
#define SCAN_B     ((N_NODES + SCAN_CHUNK - 1) / SCAN_CHUNK)   // 98

typedef _Float16 f16x8 __attribute__((ext_vector_type(8)));
typedef _Float16 f16x4 __attribute__((ext_vector_type(4)));
typedef float    f32x4 __attribute__((ext_vector_type(4)));

// ---------------- CSR build ----------------

__global__ void k_init_deg(int* deg, int n) {
    int i = blockIdx.x * blockDim.x + threadIdx.x;
    if (i < n) deg[i] = 1;              // self-loop contributes 1
}

__global__ void k_hist(const int* __restrict__ dst, int* deg, int e) {
    int i = blockIdx.x * blockDim.x + threadIdx.x;
    if (i < e) atomicAdd(&deg[dst[i]], 1);
}

// hierarchical scan, stage 1: per-chunk (512 elems) exclusive scan + chunk sum
__global__ __launch_bounds__(256) void k_scan_local(
        const int* __restrict__ deg, int* __restrict__ row_ptr,
        int* __restrict__ partials, int n) {
    __shared__ int sm[256];
    int t = threadIdx.x;
    int base = blockIdx.x * SCAN_CHUNK;
    int i0 = base + 2 * t, i1 = i0 + 1;
    int a = (i0 < n) ? deg[i0] : 0;
    int b = (i1 < n) ? deg[i1] : 0;
    int s = a + b;
    sm[t] = s;
    __syncthreads();
    #pragma unroll
    for (int off = 1; off < 256; off <<= 1) {
        int u = (t >= off) ? sm[t - off] : 0;
        __syncthreads();
        sm[t] += u;
        __syncthreads();
    }
    int excl = sm[t] - s;               // exclusive prefix of pair-sums
    if (i0 < n) row_ptr[i0] = excl;
    if (i1 < n) row_ptr[i1] = excl + a;
    if (t == 255) partials[blockIdx.x] = sm[255];
}

// stage 2: scan the chunk sums (SCAN_B <= 128), write total to row_ptr[n]
__global__ __launch_bounds__(128) void k_scan_part(
        int* __restrict__ partials, int* __restrict__ row_ptr_n) {
    __shared__ int sm[128];
    int t = threadIdx.x;
    int v = (t < SCAN_B) ? partials[t] : 0;
    sm[t] = v;
    __syncthreads();
    #pragma unroll
    for (int off = 1; off < 128; off <<= 1) {
        int u = (t >= off) ? sm[t - off] : 0;
        __syncthreads();
        sm[t] += u;
        __syncthreads();
    }
    if (t < SCAN_B) partials[t] = sm[t] - v;   // exclusive
    if (t == 127) *row_ptr_n = sm[127];        // total = E + N
}

// stage 3: add chunk offsets; produce row_ptr and cursor
__global__ void k_scan_add(int* __restrict__ row_ptr, int* __restrict__ cursor,
                           const int* __restrict__ partials, int n) {
    int i = blockIdx.x * blockDim.x + threadIdx.x;
    if (i < n) {
        int v = row_ptr[i] + partials[i / SCAN_CHUNK];
        row_ptr[i] = v;
        cursor[i] = v;
    }
}

__global__ void k_fill(const int* __restrict__ src, const int* __restrict__ dst,
                       int* cursor, int* csr_src, int e, int n) {
    int i = blockIdx.x * blockDim.x + threadIdx.x;
    if (i < e) {
        int d = dst[i];
        int p = atomicAdd(&cursor[d], 1);
        csr_src[p] = src[i];
    } else if (i < e + n) {
        int v = i - e;                  // self loop
        int p = atomicAdd(&cursor[v], 1);
        csr_src[p] = v;
    }
}

// ---------------- fp32 -> f16 hi/lo split kernels ----------------

// x [N_NODES,128] -> x_hi/x_lo [M_PAD,128] (pad rows zeroed)
__global__ void k_split_x(const float* __restrict__ x,
                          _Float16* __restrict__ xh, _Float16* __restrict__ xlo) {
    int t = blockIdx.x * blockDim.x + threadIdx.x;   // one float4 per thread
    if (t >= M_PAD * (IN_CH / 4)) return;
    int row = t / (IN_CH / 4);
    float4 v = {0.f, 0.f, 0.f, 0.f};
    if (row < N_NODES) v = ((const float4*)x)[t];
    f16x4 h = { (_Float16)v.x, (_Float16)v.y, (_Float16)v.z, (_Float16)v.w };
    f16x4 l = { (_Float16)(v.x - (float)h[0]), (_Float16)(v.y - (float)h[1]),
                (_Float16)(v.z - (float)h[2]), (_Float16)(v.w - (float)h[3]) };
    ((f16x4*)xh)[t] = h;
    ((f16x4*)xlo)[t] = l;
}

// W [K,N] -> Wt_hi/Wt_lo [N,K] (transposed, k-contiguous)
__global__ void k_split_w(const float* __restrict__ W,
                          _Float16* __restrict__ wh, _Float16* __restrict__ wl,
                          int K, int N) {
    int t = blockIdx.x * blockDim.x + threadIdx.x;
    if (t >= K * N) return;
    int n = t / K, k = t - n * K;
    float v = W[(size_t)k * N + n];
    _Float16 h = (_Float16)v;
    wh[t] = h;
    wl[t] = (_Float16)(v - (float)h);
}

// ---------------- f16-split MFMA GEMM ----------------
// z=0: C = A@W0 -> Cf16 (the gathered xl side); z=1: C = A@W1 -> Cf32 (xr).
// 3-term split: Ah*Bh + Ah*Bl + Al*Bh (lo*lo dropped, ~2^-22 relative).
// Tile: BM=128, BN=128, BK=32; 4 waves; wave w owns rows [w*32,w*32+32).
// mfma_f32_16x16x32_f16 layouts (m89/m91-verified):
//   A: m=lane&15, k=(lane>>4)*8+j   B: n=lane&15, k=(lane>>4)*8+j
//   C/D: col=lane&15, row=(lane>>4)*4+reg

#define BK  32
#define LDA 40   // LDS row pitch in f16 (32 + 8 pad -> 80 B, 16B-aligned)

__global__ __launch_bounds__(256) void k_gemm_mfma(
        const _Float16* __restrict__ A_hi, const _Float16* __restrict__ A_lo,
        const _Float16* __restrict__ W0h, const _Float16* __restrict__ W0l,
        const _Float16* __restrict__ W1h, const _Float16* __restrict__ W1l,
        _Float16* __restrict__ Cf16, float* __restrict__ Cf32, int K) {
    const _Float16* Wh = blockIdx.z ? W1h : W0h;
    const _Float16* Wl = blockIdx.z ? W1l : W0l;
    __shared__ _Float16 Ah[128 * LDA], Al[128 * LDA];
    __shared__ _Float16 Bh[128 * LDA], Bl[128 * LDA];
    int t = threadIdx.x;
    int lane = t & 63, wv = t >> 6;
    int quad = lane >> 4, r16 = lane & 15;
    size_t mBase = (size_t)blockIdx.x * 128;
    size_t nBase = (size_t)blockIdx.y * 128;
    int sr = t >> 2;              // staging row 0..63
    int sc = (t & 3) * 8;         // staging col (f16 units)
    f32x4 acc[2][8] = {};
    for (int k0 = 0; k0 < K; k0 += BK) {
        const _Float16* gAh = A_hi + (mBase + sr) * K + k0 + sc;
        const _Float16* gAl = A_lo + (mBase + sr) * K + k0 + sc;
        const _Float16* gBh = Wh + (nBase + sr) * K + k0 + sc;
        const _Float16* gBl = Wl + (nBase + sr) * K + k0 + sc;
        *(f16x8*)&Ah[sr * LDA + sc]        = *(const f16x8*)gAh;
        *(f16x8*)&Ah[(sr + 64) * LDA + sc] = *(const f16x8*)(gAh + (size_t)64 * K);
        *(f16x8*)&Al[sr * LDA + sc]        = *(const f16x8*)gAl;
        *(f16x8*)&Al[(sr + 64) * LDA + sc] = *(const f16x8*)(gAl + (size_t)64 * K);
        *(f16x8*)&Bh[sr * LDA + sc]        = *(const f16x8*)gBh;
        *(f16x8*)&Bh[(sr + 64) * LDA + sc] = *(const f16x8*)(gBh + (size_t)64 * K);
        *(f16x8*)&Bl[sr * LDA + sc]        = *(const f16x8*)gBl;
        *(f16x8*)&Bl[(sr + 64) * LDA + sc] = *(const f16x8*)(gBl + (size_t)64 * K);
        __syncthreads();
        f16x8 ah[2], al[2];
        #pragma unroll
        for (int mi = 0; mi < 2; ++mi) {
            int m = wv * 32 + mi * 16 + r16;
            ah[mi] = *(f16x8*)&Ah[m * LDA + quad * 8];
            al[mi] = *(f16x8*)&Al[m * LDA + quad * 8];
        }
        #pragma unroll
        for (int ni = 0; ni < 8; ++ni) {
            int n = ni * 16 + r16;
            f16x8 bhv = *(f16x8*)&Bh[n * LDA + quad * 8];
            f16x8 blv = *(f16x8*)&Bl[n * LDA + quad * 8];
            #pragma unroll
            for (int mi = 0; mi < 2; ++mi) {
                acc[mi][ni] = __builtin_amdgcn_mfma_f32_16x16x32_f16(ah[mi], bhv, acc[mi][ni], 0, 0, 0);
                acc[mi][ni] = __builtin_amdgcn_mfma_f32_16x16x32_f16(ah[mi], blv, acc[mi][ni], 0, 0, 0);
                acc[mi][ni] = __builtin_amdgcn_mfma_f32_16x16x32_f16(al[mi], bhv, acc[mi][ni], 0, 0, 0);
            }
        }
        __syncthreads();
    }
    if (blockIdx.z == 0) {
        #pragma unroll
        for (int mi = 0; mi < 2; ++mi)
            #pragma unroll
            for (int r = 0; r < 4; ++r) {
                size_t row = mBase + wv * 32 + mi * 16 + quad * 4 + r;
                _Float16* cp = Cf16 + row * 256 + nBase + r16;
                #pragma unroll
                for (int ni = 0; ni < 8; ++ni)
                    cp[ni * 16] = (_Float16)acc[mi][ni][r];
            }
    } else {
        #pragma unroll
        for (int mi = 0; mi < 2; ++mi)
            #pragma unroll
            for (int r = 0; r < 4; ++r) {
                size_t row = mBase + wv * 32 + mi * 16 + quad * 4 + r;
                float* cp = Cf32 + row * 256 + nBase + r16;
                #pragma unroll
                for (int ni = 0; ni < 8; ++ni)
                    cp[ni * 16] = acc[mi][ni][r];
            }
    }
}

// ---------------- edge pass: one wave per node, 4 channels per lane ----------------
// xl is stored f16 [node][256]; one edge gather = 8 B/lane (512 B/wave).

__device__ __forceinline__ float edge_w(float4 x, float4 xr, float4 att) {
    float ex = x.x + xr.x; ex = ex > 0.f ? ex : SLOPE * ex;
    float ey = x.y + xr.y; ey = ey > 0.f ? ey : SLOPE * ey;
    float ez = x.z + xr.z; ez = ez > 0.f ? ez : SLOPE * ez;
    float ew = x.w + xr.w; ew = ew > 0.f ? ew : SLOPE * ew;
    float p = ex * att.x;
    p = fmaf(ey, att.y, p);
    p = fmaf(ez, att.z, p);
    p = fmaf(ew, att.w, p);
    p += __shfl_xor(p, 1);
    p += __shfl_xor(p, 2);
    p += __shfl_xor(p, 4);
    return __expf(p);
}

__device__ __forceinline__ float4 cvt4(f16x4 v) {
    float4 r = { (float)v[0], (float)v[1], (float)v[2], (float)v[3] };
    return r;
}

__device__ __forceinline__ float4 edge_accum(
        const f16x4* __restrict__ xl4, float4 xr_v, float4 att_v,
        const int* __restrict__ csr_src, int beg, int end, int lane) {
    float4 acc = {0.f, 0.f, 0.f, 0.f};
    float S = 0.f;
    int j = beg;
    for (; j + 4 <= end; j += 4) {
        int s0 = csr_src[j];
        int s1 = csr_src[j + 1];
        int s2 = csr_src[j + 2];
        int s3 = csr_src[j + 3];
        f16x4 h0 = xl4[(size_t)s0 * 64 + lane];
        f16x4 h1 = xl4[(size_t)s1 * 64 + lane];
        f16x4 h2 = xl4[(size_t)s2 * 64 + lane];
        f16x4 h3 = xl4[(size_t)s3 * 64 + lane];
        float4 x0 = cvt4(h0);
        float4 x1 = cvt4(h1);
        float4 x2 = cvt4(h2);
        float4 x3 = cvt4(h3);
        float w0 = edge_w(x0, xr_v, att_v);
        float w1 = edge_w(x1, xr_v, att_v);
        float w2 = edge_w(x2, xr_v, att_v);
        float w3 = edge_w(x3, xr_v, att_v);
        S += (w0 + w1) + (w2 + w3);
        acc.x = fmaf(w0, x0.x, acc.x); acc.y = fmaf(w0, x0.y, acc.y);
        acc.z = fmaf(w0, x0.z, acc.z); acc.w = fmaf(w0, x0.w, acc.w);
        acc.x = fmaf(w1, x1.x, acc.x); acc.y = fmaf(w1, x1.y, acc.y);
        acc.z = fmaf(w1, x1.z, acc.z); acc.w = fmaf(w1, x1.w, acc.w);
        acc.x = fmaf(w2, x2.x, acc.x); acc.y = fmaf(w2, x2.y, acc.y);
        acc.z = fmaf(w2, x2.z, acc.z); acc.w = fmaf(w2, x2.w, acc.w);
        acc.x = fmaf(w3, x3.x, acc.x); acc.y = fmaf(w3, x3.y, acc.y);
        acc.z = fmaf(w3, x3.z, acc.z); acc.w = fmaf(w3, x3.w, acc.w);
    }
    for (; j < end; ++j) {
        int s = csr_src[j];
        float4 xv = cvt4(xl4[(size_t)s * 64 + lane]);
        float w = edge_w(xv, xr_v, att_v);
        S += w;
        acc.x = fmaf(w, xv.x, acc.x); acc.y = fmaf(w, xv.y, acc.y);
        acc.z = fmaf(w, xv.z, acc.z); acc.w = fmaf(w, xv.w, acc.w);
    }
    float inv = 1.f / S;
    acc.x *= inv; acc.y *= inv; acc.z *= inv; acc.w *= inv;
    return acc;
}

// layer 0: concat + bias + BN + ELU -> h0 written as f16 hi/lo split.
__global__ __launch_bounds__(256) void k_edge0(
        const _Float16* __restrict__ xl, const float* __restrict__ xr,
        const float* __restrict__ att,
        const int* __restrict__ row_ptr, const int* __restrict__ csr_src,
        const float* __restrict__ b0, const float* __restrict__ g0,
        const float* __restrict__ be0, const float* __restrict__ m0,
        const float* __restrict__ v0,
        _Float16* __restrict__ h0h, _Float16* __restrict__ h0l) {
    int lane = threadIdx.x & 63;
    int i = blockIdx.x * 4 + (threadIdx.x >> 6);
    const f16x4* xl4 = (const f16x4*)xl;
    float4 xr_v = ((const float4*)xr)[(size_t)i * 64 + lane];
    float4 att_v = ((const float4*)att)[lane];
    int beg = row_ptr[i], end = row_ptr[i + 1];
    float4 r = edge_accum(xl4, xr_v, att_v, csr_src, beg, end, lane);
    float4 bb = ((const float4*)b0)[lane];
    float4 gg = ((const float4*)g0)[lane];
    float4 ee = ((const float4*)be0)[lane];
    float4 mm = ((const float4*)m0)[lane];
    float4 vv = ((const float4*)v0)[lane];
    float4 o;
    o.x = (r.x + bb.x - mm.x) * rsqrtf(vv.x + BN_EPS) * gg.x + ee.x;
    o.y = (r.y + bb.y - mm.y) * rsqrtf(vv.y + BN_EPS) * gg.y + ee.y;
    o.z = (r.z + bb.z - mm.z) * rsqrtf(vv.z + BN_EPS) * gg.z + ee.z;
    o.w = (r.w + bb.w - mm.w) * rsqrtf(vv.w + BN_EPS) * gg.w + ee.w;
    o.x = o.x > 0.f ? o.x : expm1f(o.x);
    o.y = o.y > 0.f ? o.y : expm1f(o.y);
    o.z = o.z > 0.f ? o.z : expm1f(o.z);
    o.w = o.w > 0.f ? o.w : expm1f(o.w);
    f16x4 hh = { (_Float16)o.x, (_Float16)o.y, (_Float16)o.z, (_Float16)o.w };
    f16x4 hl = { (_Float16)(o.x - (float)hh[0]), (_Float16)(o.y - (float)hh[1]),
                 (_Float16)(o.z - (float)hh[2]), (_Float16)(o.w - (float)hh[3]) };
    ((f16x4*)h0h)[(size_t)i * 64 + lane] = hh;
    ((f16x4*)h0l)[(size_t)i * 64 + lane] = hl;
}

// layer 1: head-mean + bias + BN + classifier, fully in-register.
__global__ __launch_bounds__(256) void k_edge1(
        const _Float16* __restrict__ xl, const float* __restrict__ xr,
        const float* __restrict__ att,
        const int* __restrict__ row_ptr, const int* __restrict__ csr_src,
        const float* __restrict__ b1, const float* __restrict__ g1,
        const float* __restrict__ be1, const float* __restrict__ m1,
        const float* __restrict__ v1,
        const float* __restrict__ Wc, const float* __restrict__ bc,
        float* __restrict__ out) {
    int lane = threadIdx.x & 63;
    int q = lane & 7;
    int i = blockIdx.x * 4 + (threadIdx.x >> 6);
    const f16x4* xl4 = (const f16x4*)xl;
    float4 xr_v = ((const float4*)xr)[(size_t)i * 64 + lane];
    float4 att_v = ((const float4*)att)[lane];
    int beg = row_ptr[i], end = row_ptr[i + 1];
    float4 r = edge_accum(xl4, xr_v, att_v, csr_src, beg, end, lane);
    #pragma unroll
    for (int mask = 8; mask <= 32; mask <<= 1) {
        r.x += __shfl_xor(r.x, mask);
        r.y += __shfl_xor(r.y, mask);
        r.z += __shfl_xor(r.z, mask);
        r.w += __shfl_xor(r.w, mask);
    }
    float4 bb = ((const float4*)b1)[q];
    float4 gg = ((const float4*)g1)[q];
    float4 ee = ((const float4*)be1)[q];
    float4 mm = ((const float4*)m1)[q];
    float4 vv = ((const float4*)v1)[q];
    r.x = (r.x * 0.125f + bb.x - mm.x) * rsqrtf(vv.x + BN_EPS) * gg.x + ee.x;
    r.y = (r.y * 0.125f + bb.y - mm.y) * rsqrtf(vv.y + BN_EPS) * gg.y + ee.y;
    r.z = (r.z * 0.125f + bb.z - mm.z) * rsqrtf(vv.z + BN_EPS) * gg.z + ee.z;
    r.w = (r.w * 0.125f + bb.w - mm.w) * rsqrtf(vv.w + BN_EPS) * gg.w + ee.w;
    float4 wc0 = ((const float4*)Wc)[q * 2];
    float4 wc1 = ((const float4*)Wc)[q * 2 + 1];
    float o0 = r.x * wc0.x + r.y * wc0.z + r.z * wc1.x + r.w * wc1.z;
    float o1 = r.x * wc0.y + r.y * wc0.w + r.z * wc1.y + r.w * wc1.w;
    #pragma unroll
    for (int mask = 1; mask <= 4; mask <<= 1) {
        o0 += __shfl_xor(o0, mask);
        o1 += __shfl_xor(o1, mask);
    }
    if (lane == 0) {
        float2 ov = {o0 + bc[0], o1 + bc[1]};
        *(float2*)(out + (size_t)i * 2) = ov;
    }
}

// ---------------- launcher ----------------

extern "C" void kernel_launch(void* const* d_in, const int* in_sizes, int n_in,
                              void* d_out, int out_size, void* d_ws, size_t ws_size,
                              hipStream_t stream) {
    const float* x    = (const float*)d_in[0];
    const int*   ei   = (const int*)d_in[1];
    const float* Wl0  = (const float*)d_in[2];
    const float* Wr0  = (const float*)d_in[3];
    const float* att0 = (const float*)d_in[4];
    const float* b0   = (const float*)d_in[5];
    const float* g0   = (const float*)d_in[6];
    const float* be0  = (const float*)d_in[7];
    const float* m0   = (const float*)d_in[8];
    const float* v0   = (const float*)d_in[9];
    const float* Wl1  = (const float*)d_in[10];
    const float* Wr1  = (const float*)d_in[11];
    const float* att1 = (const float*)d_in[12];
    const float* b1   = (const float*)d_in[13];
    const float* g1   = (const float*)d_in[14];
    const float* be1  = (const float*)d_in[15];
    const float* m1   = (const float*)d_in[16];
    const float* v1   = (const float*)d_in[17];
    const float* Wc   = (const float*)d_in[18];
    const float* bc   = (const float*)d_in[19];
    float* out = (float*)d_out;

    const int N = N_NODES, E = E_EDGES;
    const int* srcp = ei;        // edge_index[0]
    const int* dstp = ei + E;    // edge_index[1]

    // workspace carve-up (16B-aligned chunks)
    char* p = (char*)d_ws;
    _Float16* xlf = (_Float16*)p; p += (size_t)M_PAD * HC * 2;   // xl [M_PAD,256] f16 (gather table)
    float* bufB   = (float*)p;   p += (size_t)M_PAD * HC * 4;    // xr [M_PAD,256] f32
    // shared region: h0 hi/lo (each M_PAD*256 f16) aliases x hi/lo (each M_PAD*128 f16)
    char* shared0 = p; p += (size_t)M_PAD * HC * 2 * 2;
    _Float16* h0h = (_Float16*)shared0;
    _Float16* h0l = (_Float16*)(shared0 + (size_t)M_PAD * HC * 2);
    _Float16* xh  = (_Float16*)shared0;                          // alias (dead before h0 written)
    _Float16* xlo = (_Float16*)(shared0 + (size_t)M_PAD * IN_CH * 2);
    _Float16* W0lh = (_Float16*)p; p += (size_t)HC * IN_CH * 2;  // Wt of Wl0 [256][128]
    _Float16* W0ll = (_Float16*)p; p += (size_t)HC * IN_CH * 2;
    _Float16* W0rh = (_Float16*)p; p += (size_t)HC * IN_CH * 2;
    _Float16* W0rl = (_Float16*)p; p += (size_t)HC * IN_CH * 2;
    _Float16* W1lh = (_Float16*)p; p += (size_t)HC * HC * 2;     // Wt of Wl1 [256][256]
    _Float16* W1ll = (_Float16*)p; p += (size_t)HC * HC * 2;
    _Float16* W1rh = (_Float16*)p; p += (size_t)HC * HC * 2;
    _Float16* W1rl = (_Float16*)p; p += (size_t)HC * HC * 2;
    int* deg      = (int*)p;
    int* row_ptr  = deg + N;
    int* cursor   = row_ptr + (N + 1);
    int* partials = cursor + N;
    int* csr_src  = partials + ((SCAN_B + 3) & ~3);   // E+N entries

    // CSR build (by dst)
    k_init_deg<<<(N + 255) / 256, 256, 0, stream>>>(deg, N);
    k_hist<<<(E + 255) / 256, 256, 0, stream>>>(dstp, deg, E);
    k_scan_local<<<SCAN_B, 256, 0, stream>>>(deg, row_ptr, partials, N);
    k_scan_part<<<1, 128, 0, stream>>>(partials, row_ptr + N);
    k_scan_add<<<(N + 255) / 256, 256, 0, stream>>>(row_ptr, cursor, partials, N);
    k_fill<<<(E + N + 255) / 256, 256, 0, stream>>>(srcp, dstp, cursor, csr_src, E, N);

    // splits
    k_split_x<<<(M_PAD * (IN_CH / 4) + 255) / 256, 256, 0, stream>>>(x, xh, xlo);
    k_split_w<<<(IN_CH * HC + 255) / 256, 256, 0, stream>>>(Wl0, W0lh, W0ll, IN_CH, HC);
    k_split_w<<<(IN_CH * HC + 255) / 256, 256, 0, stream>>>(Wr0, W0rh, W0rl, IN_CH, HC);
    k_split_w<<<(HC * HC + 255) / 256, 256, 0, stream>>>(Wl1, W1lh, W1ll, HC, HC);
    k_split_w<<<(HC * HC + 255) / 256, 256, 0, stream>>>(Wr1, W1rh, W1rl, HC, HC);

    dim3 ggrid(M_PAD / 128, 2, 2);
    // layer 0 projections: xl0 = x@Wl0 (f16 out), xr0 = x@Wr0 (f32 out)
    k_gemm_mfma<<<ggrid, 256, 0, stream>>>(xh, xlo, W0lh, W0ll, W0rh, W0rl,
                                           xlf, bufB, IN_CH);
    // layer 0 edge pass + BN + ELU -> h0 (f16 hi/lo)
    k_edge0<<<N / 4, 256, 0, stream>>>(xlf, bufB, att0, row_ptr, csr_src,
                                       b0, g0, be0, m0, v0, h0h, h0l);
    // layer 1 projections: xl1 = h0@Wl1 (f16 out), xr1 = h0@Wr1 (f32 out)
    k_gemm_mfma<<<ggrid, 256, 0, stream>>>(h0h, h0l, W1lh, W1ll, W1rh, W1rl,
                                           xlf, bufB, HC);
    // layer 1 edge pass + head-mean + BN + classifier -> out
    k_edge1<<<N / 4, 256, 0, stream>>>(xlf, bufB, att1, row_ptr, csr_src,
                                       b1, g1, be1, m1, v1, Wc, bc, out);
}

// Round 7
// 459.208 us; speedup vs baseline: 2.4987x; 1.0233x over previous
//
#include <hip/hip_runtime.h>
#include <math.h>

#define N_NODES 50000
#define M_PAD   50048    // 391 * 128
#define E_EDGES 800000
#define IN_CH   128
#define C_CH    32
#define H_HEADS 8
#define HC      256      // H_HEADS * C_CH
#define BN_EPS  1e-5f
#define SLOPE   0.2f

#define SCAN_CHUNK 512
#define SCAN_B     ((N_NODES + SCAN_CHUNK - 1) / SCAN_CHUNK)   // 98

typedef _Float16 f16x8 __attribute__((ext_vector_type(8)));
typedef _Float16 f16x4 __attribute__((ext_vector_type(4)));
typedef _Float16 f16x2 __attribute__((ext_vector_type(2)));
typedef float    f32x4 __attribute__((ext_vector_type(4)));

// ---------------- CSR build ----------------

__global__ void k_init_deg(int* deg, int n) {
    int i = blockIdx.x * blockDim.x + threadIdx.x;
    if (i < n) deg[i] = 1;              // self-loop contributes 1
}

__global__ void k_hist(const int* __restrict__ dst, int* deg, int e) {
    int i = blockIdx.x * blockDim.x + threadIdx.x;
    if (i < e) atomicAdd(&deg[dst[i]], 1);
}

// hierarchical scan, stage 1: per-chunk (512 elems) exclusive scan + chunk sum
__global__ __launch_bounds__(256) void k_scan_local(
        const int* __restrict__ deg, int* __restrict__ row_ptr,
        int* __restrict__ partials, int n) {
    __shared__ int sm[256];
    int t = threadIdx.x;
    int base = blockIdx.x * SCAN_CHUNK;
    int i0 = base + 2 * t, i1 = i0 + 1;
    int a = (i0 < n) ? deg[i0] : 0;
    int b = (i1 < n) ? deg[i1] : 0;
    int s = a + b;
    sm[t] = s;
    __syncthreads();
    #pragma unroll
    for (int off = 1; off < 256; off <<= 1) {
        int u = (t >= off) ? sm[t - off] : 0;
        __syncthreads();
        sm[t] += u;
        __syncthreads();
    }
    int excl = sm[t] - s;               // exclusive prefix of pair-sums
    if (i0 < n) row_ptr[i0] = excl;
    if (i1 < n) row_ptr[i1] = excl + a;
    if (t == 255) partials[blockIdx.x] = sm[255];
}

// stage 2: scan the chunk sums (SCAN_B <= 128), write total to row_ptr[n]
__global__ __launch_bounds__(128) void k_scan_part(
        int* __restrict__ partials, int* __restrict__ row_ptr_n) {
    __shared__ int sm[128];
    int t = threadIdx.x;
    int v = (t < SCAN_B) ? partials[t] : 0;
    sm[t] = v;
    __syncthreads();
    #pragma unroll
    for (int off = 1; off < 128; off <<= 1) {
        int u = (t >= off) ? sm[t - off] : 0;
        __syncthreads();
        sm[t] += u;
        __syncthreads();
    }
    if (t < SCAN_B) partials[t] = sm[t] - v;   // exclusive
    if (t == 127) *row_ptr_n = sm[127];        // total = E + N
}

// stage 3: add chunk offsets; produce row_ptr and cursor
__global__ void k_scan_add(int* __restrict__ row_ptr, int* __restrict__ cursor,
                           const int* __restrict__ partials, int n) {
    int i = blockIdx.x * blockDim.x + threadIdx.x;
    if (i < n) {
        int v = row_ptr[i] + partials[i / SCAN_CHUNK];
        row_ptr[i] = v;
        cursor[i] = v;
    }
}

__global__ void k_fill(const int* __restrict__ src, const int* __restrict__ dst,
                       int* cursor, int* csr_src, int e, int n) {
    int i = blockIdx.x * blockDim.x + threadIdx.x;
    if (i < e) {
        int d = dst[i];
        int p = atomicAdd(&cursor[d], 1);
        csr_src[p] = src[i];
    } else if (i < e + n) {
        int v = i - e;                  // self loop
        int p = atomicAdd(&cursor[v], 1);
        csr_src[p] = v;
    }
}

// ---------------- fp32 -> f16 hi/lo split kernels ----------------

// x [N_NODES,128] -> x_hi/x_lo [M_PAD,128] (pad rows zeroed)
__global__ void k_split_x(const float* __restrict__ x,
                          _Float16* __restrict__ xh, _Float16* __restrict__ xlo) {
    int t = blockIdx.x * blockDim.x + threadIdx.x;   // one float4 per thread
    if (t >= M_PAD * (IN_CH / 4)) return;
    int row = t / (IN_CH / 4);
    float4 v = {0.f, 0.f, 0.f, 0.f};
    if (row < N_NODES) v = ((const float4*)x)[t];
    f16x4 h = { (_Float16)v.x, (_Float16)v.y, (_Float16)v.z, (_Float16)v.w };
    f16x4 l = { (_Float16)(v.x - (float)h[0]), (_Float16)(v.y - (float)h[1]),
                (_Float16)(v.z - (float)h[2]), (_Float16)(v.w - (float)h[3]) };
    ((f16x4*)xh)[t] = h;
    ((f16x4*)xlo)[t] = l;
}

// W [K,N] -> Wt_hi/Wt_lo [N,K] (transposed, k-contiguous)
__global__ void k_split_w(const float* __restrict__ W,
                          _Float16* __restrict__ wh, _Float16* __restrict__ wl,
                          int K, int N) {
    int t = blockIdx.x * blockDim.x + threadIdx.x;
    if (t >= K * N) return;
    int n = t / K, k = t - n * K;
    float v = W[(size_t)k * N + n];
    _Float16 h = (_Float16)v;
    wh[t] = h;
    wl[t] = (_Float16)(v - (float)h);
}

// ---------------- f16-split MFMA GEMM ----------------
// z=0: C = A@W0 -> Cf16 (the gathered xl side); z=1: C = A@W1 -> Cf32 (xr).
// 3-term split: Ah*Bh + Ah*Bl + Al*Bh (lo*lo dropped, ~2^-22 relative).

#define BK  32
#define LDA 40   // LDS row pitch in f16 (32 + 8 pad -> 80 B, 16B-aligned)

__global__ __launch_bounds__(256) void k_gemm_mfma(
        const _Float16* __restrict__ A_hi, const _Float16* __restrict__ A_lo,
        const _Float16* __restrict__ W0h, const _Float16* __restrict__ W0l,
        const _Float16* __restrict__ W1h, const _Float16* __restrict__ W1l,
        _Float16* __restrict__ Cf16, float* __restrict__ Cf32, int K) {
    const _Float16* Wh = blockIdx.z ? W1h : W0h;
    const _Float16* Wl = blockIdx.z ? W1l : W0l;
    __shared__ _Float16 Ah[128 * LDA], Al[128 * LDA];
    __shared__ _Float16 Bh[128 * LDA], Bl[128 * LDA];
    int t = threadIdx.x;
    int lane = t & 63, wv = t >> 6;
    int quad = lane >> 4, r16 = lane & 15;
    size_t mBase = (size_t)blockIdx.x * 128;
    size_t nBase = (size_t)blockIdx.y * 128;
    int sr = t >> 2;              // staging row 0..63
    int sc = (t & 3) * 8;         // staging col (f16 units)
    f32x4 acc[2][8] = {};
    for (int k0 = 0; k0 < K; k0 += BK) {
        const _Float16* gAh = A_hi + (mBase + sr) * K + k0 + sc;
        const _Float16* gAl = A_lo + (mBase + sr) * K + k0 + sc;
        const _Float16* gBh = Wh + (nBase + sr) * K + k0 + sc;
        const _Float16* gBl = Wl + (nBase + sr) * K + k0 + sc;
        *(f16x8*)&Ah[sr * LDA + sc]        = *(const f16x8*)gAh;
        *(f16x8*)&Ah[(sr + 64) * LDA + sc] = *(const f16x8*)(gAh + (size_t)64 * K);
        *(f16x8*)&Al[sr * LDA + sc]        = *(const f16x8*)gAl;
        *(f16x8*)&Al[(sr + 64) * LDA + sc] = *(const f16x8*)(gAl + (size_t)64 * K);
        *(f16x8*)&Bh[sr * LDA + sc]        = *(const f16x8*)gBh;
        *(f16x8*)&Bh[(sr + 64) * LDA + sc] = *(const f16x8*)(gBh + (size_t)64 * K);
        *(f16x8*)&Bl[sr * LDA + sc]        = *(const f16x8*)gBl;
        *(f16x8*)&Bl[(sr + 64) * LDA + sc] = *(const f16x8*)(gBl + (size_t)64 * K);
        __syncthreads();
        f16x8 ah[2], al[2];
        #pragma unroll
        for (int mi = 0; mi < 2; ++mi) {
            int m = wv * 32 + mi * 16 + r16;
            ah[mi] = *(f16x8*)&Ah[m * LDA + quad * 8];
            al[mi] = *(f16x8*)&Al[m * LDA + quad * 8];
        }
        #pragma unroll
        for (int ni = 0; ni < 8; ++ni) {
            int n = ni * 16 + r16;
            f16x8 bhv = *(f16x8*)&Bh[n * LDA + quad * 8];
            f16x8 blv = *(f16x8*)&Bl[n * LDA + quad * 8];
            #pragma unroll
            for (int mi = 0; mi < 2; ++mi) {
                acc[mi][ni] = __builtin_amdgcn_mfma_f32_16x16x32_f16(ah[mi], bhv, acc[mi][ni], 0, 0, 0);
                acc[mi][ni] = __builtin_amdgcn_mfma_f32_16x16x32_f16(ah[mi], blv, acc[mi][ni], 0, 0, 0);
                acc[mi][ni] = __builtin_amdgcn_mfma_f32_16x16x32_f16(al[mi], bhv, acc[mi][ni], 0, 0, 0);
            }
        }
        __syncthreads();
    }
    if (blockIdx.z == 0) {
        #pragma unroll
        for (int mi = 0; mi < 2; ++mi)
            #pragma unroll
            for (int r = 0; r < 4; ++r) {
                size_t row = mBase + wv * 32 + mi * 16 + quad * 4 + r;
                _Float16* cp = Cf16 + row * 256 + nBase + r16;
                #pragma unroll
                for (int ni = 0; ni < 8; ++ni)
                    cp[ni * 16] = (_Float16)acc[mi][ni][r];
            }
    } else {
        #pragma unroll
        for (int mi = 0; mi < 2; ++mi)
            #pragma unroll
            for (int r = 0; r < 4; ++r) {
                size_t row = mBase + wv * 32 + mi * 16 + quad * 4 + r;
                float* cp = Cf32 + row * 256 + nBase + r16;
                #pragma unroll
                for (int ni = 0; ni < 8; ++ni)
                    cp[ni * 16] = acc[mi][ni][r];
            }
    }
}

// ---------------- edge pass: one wave per node, 4 channels per lane ----------------
// xl stored f16 [node][256]; one edge gather = 8 B/lane (512 B/wave).
// Logit pipeline in packed f16: v_pk_add / v_pk_mul / v_pk_max + v_dot2_f32_f16;
// value accumulate via v_fma_mix (f16 source, f32 accumulator).

__device__ __forceinline__ float edge_w16(f16x4 h, f16x4 xr, f16x4 att) {
    f16x4 e = h + xr;                                    // 2x v_pk_add_f16
    f16x4 es = e * (_Float16)SLOPE;                      // 2x v_pk_mul_f16
    f16x4 l = __builtin_elementwise_max(e, es);          // 2x v_pk_max_f16 (slope<1)
#if __has_builtin(__builtin_amdgcn_fdot2)
    f16x2 l01 = __builtin_shufflevector(l, l, 0, 1);
    f16x2 l23 = __builtin_shufflevector(l, l, 2, 3);
    f16x2 a01 = __builtin_shufflevector(att, att, 0, 1);
    f16x2 a23 = __builtin_shufflevector(att, att, 2, 3);
    float p = __builtin_amdgcn_fdot2(l01, a01, 0.f, false);
    p = __builtin_amdgcn_fdot2(l23, a23, p, false);
#else
    float p = (float)l[0] * (float)att[0];
    p = fmaf((float)l[1], (float)att[1], p);
    p = fmaf((float)l[2], (float)att[2], p);
    p = fmaf((float)l[3], (float)att[3], p);
#endif
    p += __shfl_xor(p, 1);
    p += __shfl_xor(p, 2);
    p += __shfl_xor(p, 4);
    return __expf(p);
}

__device__ __forceinline__ float4 edge_accum(
        const f16x4* __restrict__ xl4, f16x4 xr_h, f16x4 att_h,
        const int* __restrict__ csr_src, int beg, int end, int lane) {
    const f16x4* xlp = xl4 + lane;          // lane-biased base: addr = s*512B
    float4 acc = {0.f, 0.f, 0.f, 0.f};
    float S = 0.f;
    int j = beg;
    for (; j + 4 <= end; j += 4) {
        int s0 = csr_src[j];
        int s1 = csr_src[j + 1];
        int s2 = csr_src[j + 2];
        int s3 = csr_src[j + 3];
        f16x4 h0 = xlp[(size_t)s0 * 64];
        f16x4 h1 = xlp[(size_t)s1 * 64];
        f16x4 h2 = xlp[(size_t)s2 * 64];
        f16x4 h3 = xlp[(size_t)s3 * 64];
        float w0 = edge_w16(h0, xr_h, att_h);
        float w1 = edge_w16(h1, xr_h, att_h);
        float w2 = edge_w16(h2, xr_h, att_h);
        float w3 = edge_w16(h3, xr_h, att_h);
        S += (w0 + w1) + (w2 + w3);
        acc.x = fmaf((float)h0[0], w0, acc.x); acc.y = fmaf((float)h0[1], w0, acc.y);
        acc.z = fmaf((float)h0[2], w0, acc.z); acc.w = fmaf((float)h0[3], w0, acc.w);
        acc.x = fmaf((float)h1[0], w1, acc.x); acc.y = fmaf((float)h1[1], w1, acc.y);
        acc.z = fmaf((float)h1[2], w1, acc.z); acc.w = fmaf((float)h1[3], w1, acc.w);
        acc.x = fmaf((float)h2[0], w2, acc.x); acc.y = fmaf((float)h2[1], w2, acc.y);
        acc.z = fmaf((float)h2[2], w2, acc.z); acc.w = fmaf((float)h2[3], w2, acc.w);
        acc.x = fmaf((float)h3[0], w3, acc.x); acc.y = fmaf((float)h3[1], w3, acc.y);
        acc.z = fmaf((float)h3[2], w3, acc.z); acc.w = fmaf((float)h3[3], w3, acc.w);
    }
    for (; j < end; ++j) {
        int s = csr_src[j];
        f16x4 hv = xlp[(size_t)s * 64];
        float w = edge_w16(hv, xr_h, att_h);
        S += w;
        acc.x = fmaf((float)hv[0], w, acc.x); acc.y = fmaf((float)hv[1], w, acc.y);
        acc.z = fmaf((float)hv[2], w, acc.z); acc.w = fmaf((float)hv[3], w, acc.w);
    }
    float inv = 1.f / S;
    acc.x *= inv; acc.y *= inv; acc.z *= inv; acc.w *= inv;
    return acc;
}

__device__ __forceinline__ f16x4 cvt_h4(float4 v) {
    f16x4 r = { (_Float16)v.x, (_Float16)v.y, (_Float16)v.z, (_Float16)v.w };
    return r;
}

// layer 0: concat + bias + BN + ELU -> h0 written as f16 hi/lo split.
__global__ __launch_bounds__(256) void k_edge0(
        const _Float16* __restrict__ xl, const float* __restrict__ xr,
        const float* __restrict__ att,
        const int* __restrict__ row_ptr, const int* __restrict__ csr_src,
        const float* __restrict__ b0, const float* __restrict__ g0,
        const float* __restrict__ be0, const float* __restrict__ m0,
        const float* __restrict__ v0,
        _Float16* __restrict__ h0h, _Float16* __restrict__ h0l) {
    int lane = threadIdx.x & 63;
    int i = blockIdx.x * 4 + (threadIdx.x >> 6);
    const f16x4* xl4 = (const f16x4*)xl;
    f16x4 xr_h = cvt_h4(((const float4*)xr)[(size_t)i * 64 + lane]);
    f16x4 att_h = cvt_h4(((const float4*)att)[lane]);
    int beg = row_ptr[i], end = row_ptr[i + 1];
    float4 r = edge_accum(xl4, xr_h, att_h, csr_src, beg, end, lane);
    float4 bb = ((const float4*)b0)[lane];
    float4 gg = ((const float4*)g0)[lane];
    float4 ee = ((const float4*)be0)[lane];
    float4 mm = ((const float4*)m0)[lane];
    float4 vv = ((const float4*)v0)[lane];
    float4 o;
    o.x = (r.x + bb.x - mm.x) * rsqrtf(vv.x + BN_EPS) * gg.x + ee.x;
    o.y = (r.y + bb.y - mm.y) * rsqrtf(vv.y + BN_EPS) * gg.y + ee.y;
    o.z = (r.z + bb.z - mm.z) * rsqrtf(vv.z + BN_EPS) * gg.z + ee.z;
    o.w = (r.w + bb.w - mm.w) * rsqrtf(vv.w + BN_EPS) * gg.w + ee.w;
    o.x = o.x > 0.f ? o.x : expm1f(o.x);
    o.y = o.y > 0.f ? o.y : expm1f(o.y);
    o.z = o.z > 0.f ? o.z : expm1f(o.z);
    o.w = o.w > 0.f ? o.w : expm1f(o.w);
    f16x4 hh = { (_Float16)o.x, (_Float16)o.y, (_Float16)o.z, (_Float16)o.w };
    f16x4 hl = { (_Float16)(o.x - (float)hh[0]), (_Float16)(o.y - (float)hh[1]),
                 (_Float16)(o.z - (float)hh[2]), (_Float16)(o.w - (float)hh[3]) };
    ((f16x4*)h0h)[(size_t)i * 64 + lane] = hh;
    ((f16x4*)h0l)[(size_t)i * 64 + lane] = hl;
}

// layer 1: head-mean + bias + BN + classifier, fully in-register.
__global__ __launch_bounds__(256) void k_edge1(
        const _Float16* __restrict__ xl, const float* __restrict__ xr,
        const float* __restrict__ att,
        const int* __restrict__ row_ptr, const int* __restrict__ csr_src,
        const float* __restrict__ b1, const float* __restrict__ g1,
        const float* __restrict__ be1, const float* __restrict__ m1,
        const float* __restrict__ v1,
        const float* __restrict__ Wc, const float* __restrict__ bc,
        float* __restrict__ out) {
    int lane = threadIdx.x & 63;
    int q = lane & 7;
    int i = blockIdx.x * 4 + (threadIdx.x >> 6);
    const f16x4* xl4 = (const f16x4*)xl;
    f16x4 xr_h = cvt_h4(((const float4*)xr)[(size_t)i * 64 + lane]);
    f16x4 att_h = cvt_h4(((const float4*)att)[lane]);
    int beg = row_ptr[i], end = row_ptr[i + 1];
    float4 r = edge_accum(xl4, xr_h, att_h, csr_src, beg, end, lane);
    #pragma unroll
    for (int mask = 8; mask <= 32; mask <<= 1) {
        r.x += __shfl_xor(r.x, mask);
        r.y += __shfl_xor(r.y, mask);
        r.z += __shfl_xor(r.z, mask);
        r.w += __shfl_xor(r.w, mask);
    }
    float4 bb = ((const float4*)b1)[q];
    float4 gg = ((const float4*)g1)[q];
    float4 ee = ((const float4*)be1)[q];
    float4 mm = ((const float4*)m1)[q];
    float4 vv = ((const float4*)v1)[q];
    r.x = (r.x * 0.125f + bb.x - mm.x) * rsqrtf(vv.x + BN_EPS) * gg.x + ee.x;
    r.y = (r.y * 0.125f + bb.y - mm.y) * rsqrtf(vv.y + BN_EPS) * gg.y + ee.y;
    r.z = (r.z * 0.125f + bb.z - mm.z) * rsqrtf(vv.z + BN_EPS) * gg.z + ee.z;
    r.w = (r.w * 0.125f + bb.w - mm.w) * rsqrtf(vv.w + BN_EPS) * gg.w + ee.w;
    float4 wc0 = ((const float4*)Wc)[q * 2];
    float4 wc1 = ((const float4*)Wc)[q * 2 + 1];
    float o0 = r.x * wc0.x + r.y * wc0.z + r.z * wc1.x + r.w * wc1.z;
    float o1 = r.x * wc0.y + r.y * wc0.w + r.z * wc1.y + r.w * wc1.w;
    #pragma unroll
    for (int mask = 1; mask <= 4; mask <<= 1) {
        o0 += __shfl_xor(o0, mask);
        o1 += __shfl_xor(o1, mask);
    }
    if (lane == 0) {
        float2 ov = {o0 + bc[0], o1 + bc[1]};
        *(float2*)(out + (size_t)i * 2) = ov;
    }
}

// ---------------- launcher ----------------

extern "C" void kernel_launch(void* const* d_in, const int* in_sizes, int n_in,
                              void* d_out, int out_size, void* d_ws, size_t ws_size,
                              hipStream_t stream) {
    const float* x    = (const float*)d_in[0];
    const int*   ei   = (const int*)d_in[1];
    const float* Wl0  = (const float*)d_in[2];
    const float* Wr0  = (const float*)d_in[3];
    const float* att0 = (const float*)d_in[4];
    const float* b0   = (const float*)d_in[5];
    const float* g0   = (const float*)d_in[6];
    const float* be0  = (const float*)d_in[7];
    const float* m0   = (const float*)d_in[8];
    const float* v0   = (const float*)d_in[9];
    const float* Wl1  = (const float*)d_in[10];
    const float* Wr1  = (const float*)d_in[11];
    const float* att1 = (const float*)d_in[12];
    const float* b1   = (const float*)d_in[13];
    const float* g1   = (const float*)d_in[14];
    const float* be1  = (const float*)d_in[15];
    const float* m1   = (const float*)d_in[16];
    const float* v1   = (const float*)d_in[17];
    const float* Wc   = (const float*)d_in[18];
    const float* bc   = (const float*)d_in[19];
    float* out = (float*)d_out;

    const int N = N_NODES, E = E_EDGES;
    const int* srcp = ei;        // edge_index[0]
    const int* dstp = ei + E;    // edge_index[1]

    // workspace carve-up (16B-aligned chunks)
    char* p = (char*)d_ws;
    _Float16* xlf = (_Float16*)p; p += (size_t)M_PAD * HC * 2;   // xl [M_PAD,256] f16 (gather table)
    float* bufB   = (float*)p;   p += (size_t)M_PAD * HC * 4;    // xr [M_PAD,256] f32
    // shared region: h0 hi/lo (each M_PAD*256 f16) aliases x hi/lo (each M_PAD*128 f16)
    char* shared0 = p; p += (size_t)M_PAD * HC * 2 * 2;
    _Float16* h0h = (_Float16*)shared0;
    _Float16* h0l = (_Float16*)(shared0 + (size_t)M_PAD * HC * 2);
    _Float16* xh  = (_Float16*)shared0;                          // alias (dead before h0 written)
    _Float16* xlo = (_Float16*)(shared0 + (size_t)M_PAD * IN_CH * 2);
    _Float16* W0lh = (_Float16*)p; p += (size_t)HC * IN_CH * 2;  // Wt of Wl0 [256][128]
    _Float16* W0ll = (_Float16*)p; p += (size_t)HC * IN_CH * 2;
    _Float16* W0rh = (_Float16*)p; p += (size_t)HC * IN_CH * 2;
    _Float16* W0rl = (_Float16*)p; p += (size_t)HC * IN_CH * 2;
    _Float16* W1lh = (_Float16*)p; p += (size_t)HC * HC * 2;     // Wt of Wl1 [256][256]
    _Float16* W1ll = (_Float16*)p; p += (size_t)HC * HC * 2;
    _Float16* W1rh = (_Float16*)p; p += (size_t)HC * HC * 2;
    _Float16* W1rl = (_Float16*)p; p += (size_t)HC * HC * 2;
    int* deg      = (int*)p;
    int* row_ptr  = deg + N;
    int* cursor   = row_ptr + (N + 1);
    int* partials = cursor + N;
    int* csr_src  = partials + ((SCAN_B + 3) & ~3);   // E+N entries

    // CSR build (by dst)
    k_init_deg<<<(N + 255) / 256, 256, 0, stream>>>(deg, N);
    k_hist<<<(E + 255) / 256, 256, 0, stream>>>(dstp, deg, E);
    k_scan_local<<<SCAN_B, 256, 0, stream>>>(deg, row_ptr, partials, N);
    k_scan_part<<<1, 128, 0, stream>>>(partials, row_ptr + N);
    k_scan_add<<<(N + 255) / 256, 256, 0, stream>>>(row_ptr, cursor, partials, N);
    k_fill<<<(E + N + 255) / 256, 256, 0, stream>>>(srcp, dstp, cursor, csr_src, E, N);

    // splits
    k_split_x<<<(M_PAD * (IN_CH / 4) + 255) / 256, 256, 0, stream>>>(x, xh, xlo);
    k_split_w<<<(IN_CH * HC + 255) / 256, 256, 0, stream>>>(Wl0, W0lh, W0ll, IN_CH, HC);
    k_split_w<<<(IN_CH * HC + 255) / 256, 256, 0, stream>>>(Wr0, W0rh, W0rl, IN_CH, HC);
    k_split_w<<<(HC * HC + 255) / 256, 256, 0, stream>>>(Wl1, W1lh, W1ll, HC, HC);
    k_split_w<<<(HC * HC + 255) / 256, 256, 0, stream>>>(Wr1, W1rh, W1rl, HC, HC);

    dim3 ggrid(M_PAD / 128, 2, 2);
    // layer 0 projections: xl0 = x@Wl0 (f16 out), xr0 = x@Wr0 (f32 out)
    k_gemm_mfma<<<ggrid, 256, 0, stream>>>(xh, xlo, W0lh, W0ll, W0rh, W0rl,
                                           xlf, bufB, IN_CH);
    // layer 0 edge pass + BN + ELU -> h0 (f16 hi/lo)
    k_edge0<<<N / 4, 256, 0, stream>>>(xlf, bufB, att0, row_ptr, csr_src,
                                       b0, g0, be0, m0, v0, h0h, h0l);
    // layer 1 projections: xl1 = h0@Wl1 (f16 out), xr1 = h0@Wr1 (f32 out)
    k_gemm_mfma<<<ggrid, 256, 0, stream>>>(h0h, h0l, W1lh, W1ll, W1rh, W1rl,
                                           xlf, bufB, HC);
    // layer 1 edge pass + head-mean + BN + classifier -> out
    k_edge1<<<N / 4, 256, 0, stream>>>(xlf, bufB, att1, row_ptr, csr_src,
                                       b1, g1, be1, m1, v1, Wc, bc, out);
}

// Round 8
// 426.353 us; speedup vs baseline: 2.6912x; 1.0771x over previous
//
#include <hip/hip_runtime.h>
#include <math.h>

#define N_NODES 50000
#define M_PAD   50048    // 391 * 128
#define E_EDGES 800000
#define IN_CH   128
#define C_CH    32
#define H_HEADS 8
#define HC      256      // H_HEADS * C_CH
#define BN_EPS  1e-5f
#define SLOPE   0.2f

#define SCAN_CHUNK 512
#define SCAN_B     ((N_NODES + SCAN_CHUNK - 1) / SCAN_CHUNK)   // 98

typedef _Float16 f16x8 __attribute__((ext_vector_type(8)));
typedef _Float16 f16x4 __attribute__((ext_vector_type(4)));
typedef _Float16 f16x2 __attribute__((ext_vector_type(2)));
typedef float    f32x4 __attribute__((ext_vector_type(4)));

// ---------------- CSR build ----------------

__global__ void k_init_deg(int* deg, int n) {
    int i = blockIdx.x * blockDim.x + threadIdx.x;
    if (i < n) deg[i] = 1;              // self-loop contributes 1
}

__global__ void k_hist(const int* __restrict__ dst, int* deg, int e) {
    int i = blockIdx.x * blockDim.x + threadIdx.x;
    if (i < e) atomicAdd(&deg[dst[i]], 1);
}

// hierarchical scan, stage 1: per-chunk (512 elems) exclusive scan + chunk sum
__global__ __launch_bounds__(256) void k_scan_local(
        const int* __restrict__ deg, int* __restrict__ row_ptr,
        int* __restrict__ partials, int n) {
    __shared__ int sm[256];
    int t = threadIdx.x;
    int base = blockIdx.x * SCAN_CHUNK;
    int i0 = base + 2 * t, i1 = i0 + 1;
    int a = (i0 < n) ? deg[i0] : 0;
    int b = (i1 < n) ? deg[i1] : 0;
    int s = a + b;
    sm[t] = s;
    __syncthreads();
    #pragma unroll
    for (int off = 1; off < 256; off <<= 1) {
        int u = (t >= off) ? sm[t - off] : 0;
        __syncthreads();
        sm[t] += u;
        __syncthreads();
    }
    int excl = sm[t] - s;               // exclusive prefix of pair-sums
    if (i0 < n) row_ptr[i0] = excl;
    if (i1 < n) row_ptr[i1] = excl + a;
    if (t == 255) partials[blockIdx.x] = sm[255];
}

// stage 2: scan the chunk sums (SCAN_B <= 128), write total to row_ptr[n]
__global__ __launch_bounds__(128) void k_scan_part(
        int* __restrict__ partials, int* __restrict__ row_ptr_n) {
    __shared__ int sm[128];
    int t = threadIdx.x;
    int v = (t < SCAN_B) ? partials[t] : 0;
    sm[t] = v;
    __syncthreads();
    #pragma unroll
    for (int off = 1; off < 128; off <<= 1) {
        int u = (t >= off) ? sm[t - off] : 0;
        __syncthreads();
        sm[t] += u;
        __syncthreads();
    }
    if (t < SCAN_B) partials[t] = sm[t] - v;   // exclusive
    if (t == 127) *row_ptr_n = sm[127];        // total = E + N
}

// stage 3: add chunk offsets; produce row_ptr and cursor
__global__ void k_scan_add(int* __restrict__ row_ptr, int* __restrict__ cursor,
                           const int* __restrict__ partials, int n) {
    int i = blockIdx.x * blockDim.x + threadIdx.x;
    if (i < n) {
        int v = row_ptr[i] + partials[i / SCAN_CHUNK];
        row_ptr[i] = v;
        cursor[i] = v;
    }
}

__global__ void k_fill(const int* __restrict__ src, const int* __restrict__ dst,
                       int* cursor, int* csr_src, int e, int n) {
    int i = blockIdx.x * blockDim.x + threadIdx.x;
    if (i < e) {
        int d = dst[i];
        int p = atomicAdd(&cursor[d], 1);
        csr_src[p] = src[i];
    } else if (i < e + n) {
        int v = i - e;                  // self loop
        int p = atomicAdd(&cursor[v], 1);
        csr_src[p] = v;
    }
}

// ---------------- precision prep kernels ----------------

// x [N_NODES,128] -> x_f16 [M_PAD,128] (pad rows zeroed).
// A-side single-f16 is enough: x~N(0,1), K=128, W~0.09 -> dot err ~2e-4.
__global__ void k_split_x(const float* __restrict__ x, _Float16* __restrict__ xf) {
    int t = blockIdx.x * blockDim.x + threadIdx.x;   // one float4 per thread
    if (t >= M_PAD * (IN_CH / 4)) return;
    int row = t / (IN_CH / 4);
    float4 v = {0.f, 0.f, 0.f, 0.f};
    if (row < N_NODES) v = ((const float4*)x)[t];
    f16x4 h = { (_Float16)v.x, (_Float16)v.y, (_Float16)v.z, (_Float16)v.w };
    ((f16x4*)xf)[t] = h;
}

// W [K,N] -> Wt_hi/Wt_lo [N,K] (transposed, k-contiguous); B keeps hi/lo split.
__global__ void k_split_w(const float* __restrict__ W,
                          _Float16* __restrict__ wh, _Float16* __restrict__ wl,
                          int K, int N) {
    int t = blockIdx.x * blockDim.x + threadIdx.x;
    if (t >= K * N) return;
    int n = t / K, k = t - n * K;
    float v = W[(size_t)k * N + n];
    _Float16 h = (_Float16)v;
    wh[t] = h;
    wl[t] = (_Float16)(v - (float)h);
}

// ---------------- f16 MFMA GEMM (B split hi/lo, 2-term) ----------------
// z=0: C0 = A@W0 -> f16 xl table; z=1: C1 = A@W1 -> f16 xr table.
// C = A*(Bh+Bl): B split kills weight-quantization error (~2^-21);
// A single f16 adds ~2^-11 relative on activations (within threshold).
// Tile: BM=128, BN=128, BK=32; 4 waves; wave w owns rows [w*32,w*32+32).
// mfma_f32_16x16x32_f16 layouts (m89/m91-verified):
//   A: m=lane&15, k=(lane>>4)*8+j   B: n=lane&15, k=(lane>>4)*8+j
//   C/D: col=lane&15, row=(lane>>4)*4+reg

#define BK  32
#define LDA 40   // LDS row pitch in f16 (32 + 8 pad -> 80 B, 16B-aligned)

__global__ __launch_bounds__(256) void k_gemm_mfma(
        const _Float16* __restrict__ A,
        const _Float16* __restrict__ W0h, const _Float16* __restrict__ W0l,
        const _Float16* __restrict__ W1h, const _Float16* __restrict__ W1l,
        _Float16* __restrict__ C0, _Float16* __restrict__ C1, int K) {
    const _Float16* Wh = blockIdx.z ? W1h : W0h;
    const _Float16* Wl = blockIdx.z ? W1l : W0l;
    _Float16* C = blockIdx.z ? C1 : C0;
    __shared__ _Float16 As[128 * LDA];
    __shared__ _Float16 Bh[128 * LDA], Bl[128 * LDA];
    int t = threadIdx.x;
    int lane = t & 63, wv = t >> 6;
    int quad = lane >> 4, r16 = lane & 15;
    size_t mBase = (size_t)blockIdx.x * 128;
    size_t nBase = (size_t)blockIdx.y * 128;
    int sr = t >> 2;              // staging row 0..63
    int sc = (t & 3) * 8;         // staging col (f16 units)
    f32x4 acc[2][8] = {};
    for (int k0 = 0; k0 < K; k0 += BK) {
        const _Float16* gA  = A + (mBase + sr) * K + k0 + sc;
        const _Float16* gBh = Wh + (nBase + sr) * K + k0 + sc;
        const _Float16* gBl = Wl + (nBase + sr) * K + k0 + sc;
        *(f16x8*)&As[sr * LDA + sc]        = *(const f16x8*)gA;
        *(f16x8*)&As[(sr + 64) * LDA + sc] = *(const f16x8*)(gA + (size_t)64 * K);
        *(f16x8*)&Bh[sr * LDA + sc]        = *(const f16x8*)gBh;
        *(f16x8*)&Bh[(sr + 64) * LDA + sc] = *(const f16x8*)(gBh + (size_t)64 * K);
        *(f16x8*)&Bl[sr * LDA + sc]        = *(const f16x8*)gBl;
        *(f16x8*)&Bl[(sr + 64) * LDA + sc] = *(const f16x8*)(gBl + (size_t)64 * K);
        __syncthreads();
        f16x8 av[2];
        #pragma unroll
        for (int mi = 0; mi < 2; ++mi) {
            int m = wv * 32 + mi * 16 + r16;
            av[mi] = *(f16x8*)&As[m * LDA + quad * 8];
        }
        #pragma unroll
        for (int ni = 0; ni < 8; ++ni) {
            int n = ni * 16 + r16;
            f16x8 bhv = *(f16x8*)&Bh[n * LDA + quad * 8];
            f16x8 blv = *(f16x8*)&Bl[n * LDA + quad * 8];
            #pragma unroll
            for (int mi = 0; mi < 2; ++mi) {
                acc[mi][ni] = __builtin_amdgcn_mfma_f32_16x16x32_f16(av[mi], bhv, acc[mi][ni], 0, 0, 0);
                acc[mi][ni] = __builtin_amdgcn_mfma_f32_16x16x32_f16(av[mi], blv, acc[mi][ni], 0, 0, 0);
            }
        }
        __syncthreads();
    }
    #pragma unroll
    for (int mi = 0; mi < 2; ++mi)
        #pragma unroll
        for (int r = 0; r < 4; ++r) {
            size_t row = mBase + wv * 32 + mi * 16 + quad * 4 + r;
            _Float16* cp = C + row * 256 + nBase + r16;
            #pragma unroll
            for (int ni = 0; ni < 8; ++ni)
                cp[ni * 16] = (_Float16)acc[mi][ni][r];
        }
}

// ---------------- edge pass: one wave per node, 4 channels per lane ----------------
// xl and xr both f16 [node][256]; edge gather = 8 B/lane (512 B/wave).
// Logit pipeline in packed f16: v_pk_add / v_pk_mul / v_pk_max + v_dot2_f32_f16.

__device__ __forceinline__ float edge_w16(f16x4 h, f16x4 xr, f16x4 att) {
    f16x4 e = h + xr;                                    // 2x v_pk_add_f16
    f16x4 es = e * (_Float16)SLOPE;                      // 2x v_pk_mul_f16
    f16x4 l = __builtin_elementwise_max(e, es);          // 2x v_pk_max_f16 (slope<1)
#if __has_builtin(__builtin_amdgcn_fdot2)
    f16x2 l01 = __builtin_shufflevector(l, l, 0, 1);
    f16x2 l23 = __builtin_shufflevector(l, l, 2, 3);
    f16x2 a01 = __builtin_shufflevector(att, att, 0, 1);
    f16x2 a23 = __builtin_shufflevector(att, att, 2, 3);
    float p = __builtin_amdgcn_fdot2(l01, a01, 0.f, false);
    p = __builtin_amdgcn_fdot2(l23, a23, p, false);
#else
    float p = (float)l[0] * (float)att[0];
    p = fmaf((float)l[1], (float)att[1], p);
    p = fmaf((float)l[2], (float)att[2], p);
    p = fmaf((float)l[3], (float)att[3], p);
#endif
    p += __shfl_xor(p, 1);
    p += __shfl_xor(p, 2);
    p += __shfl_xor(p, 4);
    return __expf(p);
}

__device__ __forceinline__ float4 edge_accum(
        const f16x4* __restrict__ xl4, f16x4 xr_h, f16x4 att_h,
        const int* __restrict__ csr_src, int beg, int end, int lane) {
    const f16x4* xlp = xl4 + lane;          // lane-biased base: addr = s*512B
    float4 acc = {0.f, 0.f, 0.f, 0.f};
    float S = 0.f;
    int j = beg;
    for (; j + 4 <= end; j += 4) {
        int s0 = csr_src[j];
        int s1 = csr_src[j + 1];
        int s2 = csr_src[j + 2];
        int s3 = csr_src[j + 3];
        f16x4 h0 = xlp[(size_t)s0 * 64];
        f16x4 h1 = xlp[(size_t)s1 * 64];
        f16x4 h2 = xlp[(size_t)s2 * 64];
        f16x4 h3 = xlp[(size_t)s3 * 64];
        float w0 = edge_w16(h0, xr_h, att_h);
        float w1 = edge_w16(h1, xr_h, att_h);
        float w2 = edge_w16(h2, xr_h, att_h);
        float w3 = edge_w16(h3, xr_h, att_h);
        S += (w0 + w1) + (w2 + w3);
        acc.x = fmaf((float)h0[0], w0, acc.x); acc.y = fmaf((float)h0[1], w0, acc.y);
        acc.z = fmaf((float)h0[2], w0, acc.z); acc.w = fmaf((float)h0[3], w0, acc.w);
        acc.x = fmaf((float)h1[0], w1, acc.x); acc.y = fmaf((float)h1[1], w1, acc.y);
        acc.z = fmaf((float)h1[2], w1, acc.z); acc.w = fmaf((float)h1[3], w1, acc.w);
        acc.x = fmaf((float)h2[0], w2, acc.x); acc.y = fmaf((float)h2[1], w2, acc.y);
        acc.z = fmaf((float)h2[2], w2, acc.z); acc.w = fmaf((float)h2[3], w2, acc.w);
        acc.x = fmaf((float)h3[0], w3, acc.x); acc.y = fmaf((float)h3[1], w3, acc.y);
        acc.z = fmaf((float)h3[2], w3, acc.z); acc.w = fmaf((float)h3[3], w3, acc.w);
    }
    for (; j < end; ++j) {
        int s = csr_src[j];
        f16x4 hv = xlp[(size_t)s * 64];
        float w = edge_w16(hv, xr_h, att_h);
        S += w;
        acc.x = fmaf((float)hv[0], w, acc.x); acc.y = fmaf((float)hv[1], w, acc.y);
        acc.z = fmaf((float)hv[2], w, acc.z); acc.w = fmaf((float)hv[3], w, acc.w);
    }
    float inv = 1.f / S;
    acc.x *= inv; acc.y *= inv; acc.z *= inv; acc.w *= inv;
    return acc;
}

__device__ __forceinline__ f16x4 cvt_h4(float4 v) {
    f16x4 r = { (_Float16)v.x, (_Float16)v.y, (_Float16)v.z, (_Float16)v.w };
    return r;
}

// layer 0: concat + bias + BN + ELU -> h0 (f16).
__global__ __launch_bounds__(256) void k_edge0(
        const _Float16* __restrict__ xl, const _Float16* __restrict__ xr,
        const float* __restrict__ att,
        const int* __restrict__ row_ptr, const int* __restrict__ csr_src,
        const float* __restrict__ b0, const float* __restrict__ g0,
        const float* __restrict__ be0, const float* __restrict__ m0,
        const float* __restrict__ v0,
        _Float16* __restrict__ h0) {
    int lane = threadIdx.x & 63;
    int i = blockIdx.x * 4 + (threadIdx.x >> 6);
    const f16x4* xl4 = (const f16x4*)xl;
    f16x4 xr_h = ((const f16x4*)xr)[(size_t)i * 64 + lane];
    f16x4 att_h = cvt_h4(((const float4*)att)[lane]);
    int beg = row_ptr[i], end = row_ptr[i + 1];
    float4 r = edge_accum(xl4, xr_h, att_h, csr_src, beg, end, lane);
    float4 bb = ((const float4*)b0)[lane];
    float4 gg = ((const float4*)g0)[lane];
    float4 ee = ((const float4*)be0)[lane];
    float4 mm = ((const float4*)m0)[lane];
    float4 vv = ((const float4*)v0)[lane];
    float4 o;
    o.x = (r.x + bb.x - mm.x) * rsqrtf(vv.x + BN_EPS) * gg.x + ee.x;
    o.y = (r.y + bb.y - mm.y) * rsqrtf(vv.y + BN_EPS) * gg.y + ee.y;
    o.z = (r.z + bb.z - mm.z) * rsqrtf(vv.z + BN_EPS) * gg.z + ee.z;
    o.w = (r.w + bb.w - mm.w) * rsqrtf(vv.w + BN_EPS) * gg.w + ee.w;
    o.x = o.x > 0.f ? o.x : expm1f(o.x);
    o.y = o.y > 0.f ? o.y : expm1f(o.y);
    o.z = o.z > 0.f ? o.z : expm1f(o.z);
    o.w = o.w > 0.f ? o.w : expm1f(o.w);
    f16x4 hh = { (_Float16)o.x, (_Float16)o.y, (_Float16)o.z, (_Float16)o.w };
    ((f16x4*)h0)[(size_t)i * 64 + lane] = hh;
}

// layer 1: head-mean + bias + BN + classifier, fully in-register.
__global__ __launch_bounds__(256) void k_edge1(
        const _Float16* __restrict__ xl, const _Float16* __restrict__ xr,
        const float* __restrict__ att,
        const int* __restrict__ row_ptr, const int* __restrict__ csr_src,
        const float* __restrict__ b1, const float* __restrict__ g1,
        const float* __restrict__ be1, const float* __restrict__ m1,
        const float* __restrict__ v1,
        const float* __restrict__ Wc, const float* __restrict__ bc,
        float* __restrict__ out) {
    int lane = threadIdx.x & 63;
    int q = lane & 7;
    int i = blockIdx.x * 4 + (threadIdx.x >> 6);
    const f16x4* xl4 = (const f16x4*)xl;
    f16x4 xr_h = ((const f16x4*)xr)[(size_t)i * 64 + lane];
    f16x4 att_h = cvt_h4(((const float4*)att)[lane]);
    int beg = row_ptr[i], end = row_ptr[i + 1];
    float4 r = edge_accum(xl4, xr_h, att_h, csr_src, beg, end, lane);
    #pragma unroll
    for (int mask = 8; mask <= 32; mask <<= 1) {
        r.x += __shfl_xor(r.x, mask);
        r.y += __shfl_xor(r.y, mask);
        r.z += __shfl_xor(r.z, mask);
        r.w += __shfl_xor(r.w, mask);
    }
    float4 bb = ((const float4*)b1)[q];
    float4 gg = ((const float4*)g1)[q];
    float4 ee = ((const float4*)be1)[q];
    float4 mm = ((const float4*)m1)[q];
    float4 vv = ((const float4*)v1)[q];
    r.x = (r.x * 0.125f + bb.x - mm.x) * rsqrtf(vv.x + BN_EPS) * gg.x + ee.x;
    r.y = (r.y * 0.125f + bb.y - mm.y) * rsqrtf(vv.y + BN_EPS) * gg.y + ee.y;
    r.z = (r.z * 0.125f + bb.z - mm.z) * rsqrtf(vv.z + BN_EPS) * gg.z + ee.z;
    r.w = (r.w * 0.125f + bb.w - mm.w) * rsqrtf(vv.w + BN_EPS) * gg.w + ee.w;
    float4 wc0 = ((const float4*)Wc)[q * 2];
    float4 wc1 = ((const float4*)Wc)[q * 2 + 1];
    float o0 = r.x * wc0.x + r.y * wc0.z + r.z * wc1.x + r.w * wc1.z;
    float o1 = r.x * wc0.y + r.y * wc0.w + r.z * wc1.y + r.w * wc1.w;
    #pragma unroll
    for (int mask = 1; mask <= 4; mask <<= 1) {
        o0 += __shfl_xor(o0, mask);
        o1 += __shfl_xor(o1, mask);
    }
    if (lane == 0) {
        float2 ov = {o0 + bc[0], o1 + bc[1]};
        *(float2*)(out + (size_t)i * 2) = ov;
    }
}

// ---------------- launcher ----------------

extern "C" void kernel_launch(void* const* d_in, const int* in_sizes, int n_in,
                              void* d_out, int out_size, void* d_ws, size_t ws_size,
                              hipStream_t stream) {
    const float* x    = (const float*)d_in[0];
    const int*   ei   = (const int*)d_in[1];
    const float* Wl0  = (const float*)d_in[2];
    const float* Wr0  = (const float*)d_in[3];
    const float* att0 = (const float*)d_in[4];
    const float* b0   = (const float*)d_in[5];
    const float* g0   = (const float*)d_in[6];
    const float* be0  = (const float*)d_in[7];
    const float* m0   = (const float*)d_in[8];
    const float* v0   = (const float*)d_in[9];
    const float* Wl1  = (const float*)d_in[10];
    const float* Wr1  = (const float*)d_in[11];
    const float* att1 = (const float*)d_in[12];
    const float* b1   = (const float*)d_in[13];
    const float* g1   = (const float*)d_in[14];
    const float* be1  = (const float*)d_in[15];
    const float* m1   = (const float*)d_in[16];
    const float* v1   = (const float*)d_in[17];
    const float* Wc   = (const float*)d_in[18];
    const float* bc   = (const float*)d_in[19];
    float* out = (float*)d_out;

    const int N = N_NODES, E = E_EDGES;
    const int* srcp = ei;        // edge_index[0]
    const int* dstp = ei + E;    // edge_index[1]

    // workspace carve-up (16B-aligned chunks)
    char* p = (char*)d_ws;
    _Float16* xlf = (_Float16*)p; p += (size_t)M_PAD * HC * 2;   // xl table [M_PAD,256] f16
    _Float16* xrf = (_Float16*)p; p += (size_t)M_PAD * HC * 2;   // xr table [M_PAD,256] f16
    // shared region: h0 f16 [M_PAD,256] aliases x f16 [M_PAD,128] (disjoint lifetimes)
    char* shared0 = p; p += (size_t)M_PAD * HC * 2;
    _Float16* h0 = (_Float16*)shared0;
    _Float16* xf = (_Float16*)shared0;                           // dead after GEMM0
    _Float16* W0lh = (_Float16*)p; p += (size_t)HC * IN_CH * 2;  // Wt of Wl0 [256][128]
    _Float16* W0ll = (_Float16*)p; p += (size_t)HC * IN_CH * 2;
    _Float16* W0rh = (_Float16*)p; p += (size_t)HC * IN_CH * 2;
    _Float16* W0rl = (_Float16*)p; p += (size_t)HC * IN_CH * 2;
    _Float16* W1lh = (_Float16*)p; p += (size_t)HC * HC * 2;     // Wt of Wl1 [256][256]
    _Float16* W1ll = (_Float16*)p; p += (size_t)HC * HC * 2;
    _Float16* W1rh = (_Float16*)p; p += (size_t)HC * HC * 2;
    _Float16* W1rl = (_Float16*)p; p += (size_t)HC * HC * 2;
    int* deg      = (int*)p;
    int* row_ptr  = deg + N;
    int* cursor   = row_ptr + (N + 1);
    int* partials = cursor + N;
    int* csr_src  = partials + ((SCAN_B + 3) & ~3);   // E+N entries

    // CSR build (by dst)
    k_init_deg<<<(N + 255) / 256, 256, 0, stream>>>(deg, N);
    k_hist<<<(E + 255) / 256, 256, 0, stream>>>(dstp, deg, E);
    k_scan_local<<<SCAN_B, 256, 0, stream>>>(deg, row_ptr, partials, N);
    k_scan_part<<<1, 128, 0, stream>>>(partials, row_ptr + N);
    k_scan_add<<<(N + 255) / 256, 256, 0, stream>>>(row_ptr, cursor, partials, N);
    k_fill<<<(E + N + 255) / 256, 256, 0, stream>>>(srcp, dstp, cursor, csr_src, E, N);

    // precision prep
    k_split_x<<<(M_PAD * (IN_CH / 4) + 255) / 256, 256, 0, stream>>>(x, xf);
    k_split_w<<<(IN_CH * HC + 255) / 256, 256, 0, stream>>>(Wl0, W0lh, W0ll, IN_CH, HC);
    k_split_w<<<(IN_CH * HC + 255) / 256, 256, 0, stream>>>(Wr0, W0rh, W0rl, IN_CH, HC);
    k_split_w<<<(HC * HC + 255) / 256, 256, 0, stream>>>(Wl1, W1lh, W1ll, HC, HC);
    k_split_w<<<(HC * HC + 255) / 256, 256, 0, stream>>>(Wr1, W1rh, W1rl, HC, HC);

    dim3 ggrid(M_PAD / 128, 2, 2);
    // layer 0 projections: xl0 = x@Wl0, xr0 = x@Wr0 (both f16 out)
    k_gemm_mfma<<<ggrid, 256, 0, stream>>>(xf, W0lh, W0ll, W0rh, W0rl,
                                           xlf, xrf, IN_CH);
    // layer 0 edge pass + BN + ELU -> h0 (f16)
    k_edge0<<<N / 4, 256, 0, stream>>>(xlf, xrf, att0, row_ptr, csr_src,
                                       b0, g0, be0, m0, v0, h0);
    // layer 1 projections: xl1 = h0@Wl1, xr1 = h0@Wr1 (both f16 out)
    k_gemm_mfma<<<ggrid, 256, 0, stream>>>(h0, W1lh, W1ll, W1rh, W1rl,
                                           xlf, xrf, HC);
    // layer 1 edge pass + head-mean + BN + classifier -> out
    k_edge1<<<N / 4, 256, 0, stream>>>(xlf, xrf, att1, row_ptr, csr_src,
                                       b1, g1, be1, m1, v1, Wc, bc, out);
}

// Round 9
// 402.508 us; speedup vs baseline: 2.8506x; 1.0592x over previous
//
#include <hip/hip_runtime.h>
#include <math.h>

#define N_NODES 50000
#define M_PAD   50048    // 391 * 128
#define E_EDGES 800000
#define IN_CH   128
#define C_CH    32
#define H_HEADS 8
#define HC      256      // H_HEADS * C_CH
#define BN_EPS  1e-5f
#define SLOPE   0.2f

#define SCAN_CHUNK 512
#define SCAN_B     ((N_NODES + SCAN_CHUNK - 1) / SCAN_CHUNK)   // 98

typedef _Float16 f16x8 __attribute__((ext_vector_type(8)));
typedef _Float16 f16x4 __attribute__((ext_vector_type(4)));
typedef _Float16 f16x2 __attribute__((ext_vector_type(2)));
typedef float    f32x4 __attribute__((ext_vector_type(4)));

// ---------------- CSR build ----------------

__global__ void k_init_deg(int* deg, int n) {
    int i = blockIdx.x * blockDim.x + threadIdx.x;
    if (i < n) deg[i] = 1;              // self-loop contributes 1
}

__global__ void k_hist(const int* __restrict__ dst, int* deg, int e) {
    int i = blockIdx.x * blockDim.x + threadIdx.x;
    if (i < e) atomicAdd(&deg[dst[i]], 1);
}

// hierarchical scan, stage 1: per-chunk (512 elems) exclusive scan + chunk sum
__global__ __launch_bounds__(256) void k_scan_local(
        const int* __restrict__ deg, int* __restrict__ row_ptr,
        int* __restrict__ partials, int n) {
    __shared__ int sm[256];
    int t = threadIdx.x;
    int base = blockIdx.x * SCAN_CHUNK;
    int i0 = base + 2 * t, i1 = i0 + 1;
    int a = (i0 < n) ? deg[i0] : 0;
    int b = (i1 < n) ? deg[i1] : 0;
    int s = a + b;
    sm[t] = s;
    __syncthreads();
    #pragma unroll
    for (int off = 1; off < 256; off <<= 1) {
        int u = (t >= off) ? sm[t - off] : 0;
        __syncthreads();
        sm[t] += u;
        __syncthreads();
    }
    int excl = sm[t] - s;               // exclusive prefix of pair-sums
    if (i0 < n) row_ptr[i0] = excl;
    if (i1 < n) row_ptr[i1] = excl + a;
    if (t == 255) partials[blockIdx.x] = sm[255];
}

// stage 2: scan the chunk sums (SCAN_B <= 128), write total to row_ptr[n]
__global__ __launch_bounds__(128) void k_scan_part(
        int* __restrict__ partials, int* __restrict__ row_ptr_n) {
    __shared__ int sm[128];
    int t = threadIdx.x;
    int v = (t < SCAN_B) ? partials[t] : 0;
    sm[t] = v;
    __syncthreads();
    #pragma unroll
    for (int off = 1; off < 128; off <<= 1) {
        int u = (t >= off) ? sm[t - off] : 0;
        __syncthreads();
        sm[t] += u;
        __syncthreads();
    }
    if (t < SCAN_B) partials[t] = sm[t] - v;   // exclusive
    if (t == 127) *row_ptr_n = sm[127];        // total = E + N
}

// stage 3: add chunk offsets; produce row_ptr and cursor
__global__ void k_scan_add(int* __restrict__ row_ptr, int* __restrict__ cursor,
                           const int* __restrict__ partials, int n) {
    int i = blockIdx.x * blockDim.x + threadIdx.x;
    if (i < n) {
        int v = row_ptr[i] + partials[i / SCAN_CHUNK];
        row_ptr[i] = v;
        cursor[i] = v;
    }
}

__global__ void k_fill(const int* __restrict__ src, const int* __restrict__ dst,
                       int* cursor, int* csr_src, int e, int n) {
    int i = blockIdx.x * blockDim.x + threadIdx.x;
    if (i < e) {
        int d = dst[i];
        int p = atomicAdd(&cursor[d], 1);
        csr_src[p] = src[i];
    } else if (i < e + n) {
        int v = i - e;                  // self loop
        int p = atomicAdd(&cursor[v], 1);
        csr_src[p] = v;
    }
}

// ---------------- weight prep: all 4 W [K,256] -> Wt f16 [256][K] ----------------
// single-f16 weights: quant err ~3e-4 absolute on outputs (vs 7e-3 threshold).

__global__ void k_split_w4(const float* __restrict__ Wl0, const float* __restrict__ Wr0,
                           const float* __restrict__ Wl1, const float* __restrict__ Wr1,
                           _Float16* __restrict__ W0lt, _Float16* __restrict__ W0rt,
                           _Float16* __restrict__ W1lt, _Float16* __restrict__ W1rt) {
    int t = blockIdx.x * blockDim.x + threadIdx.x;
    const float* W; _Float16* O; int K, rel;
    if (t < 32768)       { W = Wl0; O = W0lt; K = 128; rel = t; }
    else if (t < 65536)  { W = Wr0; O = W0rt; K = 128; rel = t - 32768; }
    else if (t < 131072) { W = Wl1; O = W1lt; K = 256; rel = t - 65536; }
    else if (t < 196608) { W = Wr1; O = W1rt; K = 256; rel = t - 131072; }
    else return;
    int n = rel / K, k = rel - n * K;
    O[rel] = (_Float16)W[(size_t)k * 256 + n];
}

// ---------------- f16 MFMA GEMM (single term) ----------------
// z=0: C0 = A@W0 -> f16 xl table; z=1: C1 = A@W1 -> f16 xr table.
// A either f16 (A16) or f32 (A32, converted in staging; rows >= N_NODES -> 0).
// Tile: BM=128, BN=128, BK=32; 4 waves; wave w owns rows [w*32,w*32+32).
// mfma_f32_16x16x32_f16 layouts (m89/m91-verified):
//   A: m=lane&15, k=(lane>>4)*8+j   B: n=lane&15, k=(lane>>4)*8+j
//   C/D: col=lane&15, row=(lane>>4)*4+reg

#define BK  32
#define LDA 40   // LDS row pitch in f16 (32 + 8 pad -> 80 B, 16B-aligned)

__device__ __forceinline__ f16x8 cvt_h8(float4 a, float4 b) {
    f16x8 v = { (_Float16)a.x, (_Float16)a.y, (_Float16)a.z, (_Float16)a.w,
                (_Float16)b.x, (_Float16)b.y, (_Float16)b.z, (_Float16)b.w };
    return v;
}

__global__ __launch_bounds__(256) void k_gemm_mfma(
        const _Float16* __restrict__ A16, const float* __restrict__ A32,
        const _Float16* __restrict__ W0t, const _Float16* __restrict__ W1t,
        _Float16* __restrict__ C0, _Float16* __restrict__ C1, int K) {
    const _Float16* Wt = blockIdx.z ? W1t : W0t;
    _Float16* C = blockIdx.z ? C1 : C0;
    __shared__ _Float16 As[128 * LDA];
    __shared__ _Float16 Bs[128 * LDA];
    int t = threadIdx.x;
    int lane = t & 63, wv = t >> 6;
    int quad = lane >> 4, r16 = lane & 15;
    size_t mBase = (size_t)blockIdx.x * 128;
    size_t nBase = (size_t)blockIdx.y * 128;
    int sr = t >> 2;              // staging row 0..63
    int sc = (t & 3) * 8;         // staging col (f16 units)
    f32x4 acc[2][8] = {};
    for (int k0 = 0; k0 < K; k0 += BK) {
        if (A32) {
            size_t r0 = mBase + sr, r1 = r0 + 64;
            float4 a0 = {0.f,0.f,0.f,0.f}, a1 = a0, b0 = a0, b1 = a0;
            if (r0 < N_NODES) {
                const float* g = A32 + r0 * K + k0 + sc;
                a0 = ((const float4*)g)[0];
                a1 = ((const float4*)g)[1];
            }
            if (r1 < N_NODES) {
                const float* g = A32 + r1 * K + k0 + sc;
                b0 = ((const float4*)g)[0];
                b1 = ((const float4*)g)[1];
            }
            *(f16x8*)&As[sr * LDA + sc]        = cvt_h8(a0, a1);
            *(f16x8*)&As[(sr + 64) * LDA + sc] = cvt_h8(b0, b1);
        } else {
            const _Float16* gA = A16 + (mBase + sr) * K + k0 + sc;
            *(f16x8*)&As[sr * LDA + sc]        = *(const f16x8*)gA;
            *(f16x8*)&As[(sr + 64) * LDA + sc] = *(const f16x8*)(gA + (size_t)64 * K);
        }
        const _Float16* gB = Wt + (nBase + sr) * K + k0 + sc;
        *(f16x8*)&Bs[sr * LDA + sc]        = *(const f16x8*)gB;
        *(f16x8*)&Bs[(sr + 64) * LDA + sc] = *(const f16x8*)(gB + (size_t)64 * K);
        __syncthreads();
        f16x8 av[2];
        #pragma unroll
        for (int mi = 0; mi < 2; ++mi) {
            int m = wv * 32 + mi * 16 + r16;
            av[mi] = *(f16x8*)&As[m * LDA + quad * 8];
        }
        #pragma unroll
        for (int ni = 0; ni < 8; ++ni) {
            int n = ni * 16 + r16;
            f16x8 bv = *(f16x8*)&Bs[n * LDA + quad * 8];
            #pragma unroll
            for (int mi = 0; mi < 2; ++mi)
                acc[mi][ni] = __builtin_amdgcn_mfma_f32_16x16x32_f16(av[mi], bv, acc[mi][ni], 0, 0, 0);
        }
        __syncthreads();
    }
    #pragma unroll
    for (int mi = 0; mi < 2; ++mi)
        #pragma unroll
        for (int r = 0; r < 4; ++r) {
            size_t row = mBase + wv * 32 + mi * 16 + quad * 4 + r;
            _Float16* cp = C + row * 256 + nBase + r16;
            #pragma unroll
            for (int ni = 0; ni < 8; ++ni)
                cp[ni * 16] = (_Float16)acc[mi][ni][r];
        }
}

// ---------------- edge pass: one wave per node, 4 channels per lane ----------------
// xl and xr both f16 [node][256]; edge gather = 8 B/lane (512 B/wave).
// Logit pipeline in packed f16: v_pk_add / v_pk_mul / v_pk_max + v_dot2_f32_f16.

__device__ __forceinline__ float edge_w16(f16x4 h, f16x4 xr, f16x4 att) {
    f16x4 e = h + xr;                                    // 2x v_pk_add_f16
    f16x4 es = e * (_Float16)SLOPE;                      // 2x v_pk_mul_f16
    f16x4 l = __builtin_elementwise_max(e, es);          // 2x v_pk_max_f16 (slope<1)
#if __has_builtin(__builtin_amdgcn_fdot2)
    f16x2 l01 = __builtin_shufflevector(l, l, 0, 1);
    f16x2 l23 = __builtin_shufflevector(l, l, 2, 3);
    f16x2 a01 = __builtin_shufflevector(att, att, 0, 1);
    f16x2 a23 = __builtin_shufflevector(att, att, 2, 3);
    float p = __builtin_amdgcn_fdot2(l01, a01, 0.f, false);
    p = __builtin_amdgcn_fdot2(l23, a23, p, false);
#else
    float p = (float)l[0] * (float)att[0];
    p = fmaf((float)l[1], (float)att[1], p);
    p = fmaf((float)l[2], (float)att[2], p);
    p = fmaf((float)l[3], (float)att[3], p);
#endif
    p += __shfl_xor(p, 1);
    p += __shfl_xor(p, 2);
    p += __shfl_xor(p, 4);
    return __expf(p);
}

__device__ __forceinline__ float4 edge_accum(
        const f16x4* __restrict__ xl4, f16x4 xr_h, f16x4 att_h,
        const int* __restrict__ csr_src, int beg, int end, int lane) {
    const f16x4* xlp = xl4 + lane;          // lane-biased base: addr = s*512B
    float4 acc = {0.f, 0.f, 0.f, 0.f};
    float S = 0.f;
    int j = beg;
    for (; j + 4 <= end; j += 4) {
        int s0 = csr_src[j];
        int s1 = csr_src[j + 1];
        int s2 = csr_src[j + 2];
        int s3 = csr_src[j + 3];
        f16x4 h0 = xlp[(size_t)s0 * 64];
        f16x4 h1 = xlp[(size_t)s1 * 64];
        f16x4 h2 = xlp[(size_t)s2 * 64];
        f16x4 h3 = xlp[(size_t)s3 * 64];
        float w0 = edge_w16(h0, xr_h, att_h);
        float w1 = edge_w16(h1, xr_h, att_h);
        float w2 = edge_w16(h2, xr_h, att_h);
        float w3 = edge_w16(h3, xr_h, att_h);
        S += (w0 + w1) + (w2 + w3);
        acc.x = fmaf((float)h0[0], w0, acc.x); acc.y = fmaf((float)h0[1], w0, acc.y);
        acc.z = fmaf((float)h0[2], w0, acc.z); acc.w = fmaf((float)h0[3], w0, acc.w);
        acc.x = fmaf((float)h1[0], w1, acc.x); acc.y = fmaf((float)h1[1], w1, acc.y);
        acc.z = fmaf((float)h1[2], w1, acc.z); acc.w = fmaf((float)h1[3], w1, acc.w);
        acc.x = fmaf((float)h2[0], w2, acc.x); acc.y = fmaf((float)h2[1], w2, acc.y);
        acc.z = fmaf((float)h2[2], w2, acc.z); acc.w = fmaf((float)h2[3], w2, acc.w);
        acc.x = fmaf((float)h3[0], w3, acc.x); acc.y = fmaf((float)h3[1], w3, acc.y);
        acc.z = fmaf((float)h3[2], w3, acc.z); acc.w = fmaf((float)h3[3], w3, acc.w);
    }
    for (; j < end; ++j) {
        int s = csr_src[j];
        f16x4 hv = xlp[(size_t)s * 64];
        float w = edge_w16(hv, xr_h, att_h);
        S += w;
        acc.x = fmaf((float)hv[0], w, acc.x); acc.y = fmaf((float)hv[1], w, acc.y);
        acc.z = fmaf((float)hv[2], w, acc.z); acc.w = fmaf((float)hv[3], w, acc.w);
    }
    float inv = 1.f / S;
    acc.x *= inv; acc.y *= inv; acc.z *= inv; acc.w *= inv;
    return acc;
}

__device__ __forceinline__ f16x4 cvt_h4(float4 v) {
    f16x4 r = { (_Float16)v.x, (_Float16)v.y, (_Float16)v.z, (_Float16)v.w };
    return r;
}

// layer 0: concat + bias + BN + ELU -> h0 (f16).
__global__ __launch_bounds__(256) void k_edge0(
        const _Float16* __restrict__ xl, const _Float16* __restrict__ xr,
        const float* __restrict__ att,
        const int* __restrict__ row_ptr, const int* __restrict__ csr_src,
        const float* __restrict__ b0, const float* __restrict__ g0,
        const float* __restrict__ be0, const float* __restrict__ m0,
        const float* __restrict__ v0,
        _Float16* __restrict__ h0) {
    int lane = threadIdx.x & 63;
    int i = blockIdx.x * 4 + (threadIdx.x >> 6);
    const f16x4* xl4 = (const f16x4*)xl;
    f16x4 xr_h = ((const f16x4*)xr)[(size_t)i * 64 + lane];
    f16x4 att_h = cvt_h4(((const float4*)att)[lane]);
    int beg = row_ptr[i], end = row_ptr[i + 1];
    float4 r = edge_accum(xl4, xr_h, att_h, csr_src, beg, end, lane);
    float4 bb = ((const float4*)b0)[lane];
    float4 gg = ((const float4*)g0)[lane];
    float4 ee = ((const float4*)be0)[lane];
    float4 mm = ((const float4*)m0)[lane];
    float4 vv = ((const float4*)v0)[lane];
    float4 o;
    o.x = (r.x + bb.x - mm.x) * rsqrtf(vv.x + BN_EPS) * gg.x + ee.x;
    o.y = (r.y + bb.y - mm.y) * rsqrtf(vv.y + BN_EPS) * gg.y + ee.y;
    o.z = (r.z + bb.z - mm.z) * rsqrtf(vv.z + BN_EPS) * gg.z + ee.z;
    o.w = (r.w + bb.w - mm.w) * rsqrtf(vv.w + BN_EPS) * gg.w + ee.w;
    o.x = o.x > 0.f ? o.x : expm1f(o.x);
    o.y = o.y > 0.f ? o.y : expm1f(o.y);
    o.z = o.z > 0.f ? o.z : expm1f(o.z);
    o.w = o.w > 0.f ? o.w : expm1f(o.w);
    f16x4 hh = { (_Float16)o.x, (_Float16)o.y, (_Float16)o.z, (_Float16)o.w };
    ((f16x4*)h0)[(size_t)i * 64 + lane] = hh;
}

// layer 1: head-mean + bias + BN + classifier, fully in-register.
__global__ __launch_bounds__(256) void k_edge1(
        const _Float16* __restrict__ xl, const _Float16* __restrict__ xr,
        const float* __restrict__ att,
        const int* __restrict__ row_ptr, const int* __restrict__ csr_src,
        const float* __restrict__ b1, const float* __restrict__ g1,
        const float* __restrict__ be1, const float* __restrict__ m1,
        const float* __restrict__ v1,
        const float* __restrict__ Wc, const float* __restrict__ bc,
        float* __restrict__ out) {
    int lane = threadIdx.x & 63;
    int q = lane & 7;
    int i = blockIdx.x * 4 + (threadIdx.x >> 6);
    const f16x4* xl4 = (const f16x4*)xl;
    f16x4 xr_h = ((const f16x4*)xr)[(size_t)i * 64 + lane];
    f16x4 att_h = cvt_h4(((const float4*)att)[lane]);
    int beg = row_ptr[i], end = row_ptr[i + 1];
    float4 r = edge_accum(xl4, xr_h, att_h, csr_src, beg, end, lane);
    #pragma unroll
    for (int mask = 8; mask <= 32; mask <<= 1) {
        r.x += __shfl_xor(r.x, mask);
        r.y += __shfl_xor(r.y, mask);
        r.z += __shfl_xor(r.z, mask);
        r.w += __shfl_xor(r.w, mask);
    }
    float4 bb = ((const float4*)b1)[q];
    float4 gg = ((const float4*)g1)[q];
    float4 ee = ((const float4*)be1)[q];
    float4 mm = ((const float4*)m1)[q];
    float4 vv = ((const float4*)v1)[q];
    r.x = (r.x * 0.125f + bb.x - mm.x) * rsqrtf(vv.x + BN_EPS) * gg.x + ee.x;
    r.y = (r.y * 0.125f + bb.y - mm.y) * rsqrtf(vv.y + BN_EPS) * gg.y + ee.y;
    r.z = (r.z * 0.125f + bb.z - mm.z) * rsqrtf(vv.z + BN_EPS) * gg.z + ee.z;
    r.w = (r.w * 0.125f + bb.w - mm.w) * rsqrtf(vv.w + BN_EPS) * gg.w + ee.w;
    float4 wc0 = ((const float4*)Wc)[q * 2];
    float4 wc1 = ((const float4*)Wc)[q * 2 + 1];
    float o0 = r.x * wc0.x + r.y * wc0.z + r.z * wc1.x + r.w * wc1.z;
    float o1 = r.x * wc0.y + r.y * wc0.w + r.z * wc1.y + r.w * wc1.w;
    #pragma unroll
    for (int mask = 1; mask <= 4; mask <<= 1) {
        o0 += __shfl_xor(o0, mask);
        o1 += __shfl_xor(o1, mask);
    }
    if (lane == 0) {
        float2 ov = {o0 + bc[0], o1 + bc[1]};
        *(float2*)(out + (size_t)i * 2) = ov;
    }
}

// ---------------- launcher ----------------

extern "C" void kernel_launch(void* const* d_in, const int* in_sizes, int n_in,
                              void* d_out, int out_size, void* d_ws, size_t ws_size,
                              hipStream_t stream) {
    const float* x    = (const float*)d_in[0];
    const int*   ei   = (const int*)d_in[1];
    const float* Wl0  = (const float*)d_in[2];
    const float* Wr0  = (const float*)d_in[3];
    const float* att0 = (const float*)d_in[4];
    const float* b0   = (const float*)d_in[5];
    const float* g0   = (const float*)d_in[6];
    const float* be0  = (const float*)d_in[7];
    const float* m0   = (const float*)d_in[8];
    const float* v0   = (const float*)d_in[9];
    const float* Wl1  = (const float*)d_in[10];
    const float* Wr1  = (const float*)d_in[11];
    const float* att1 = (const float*)d_in[12];
    const float* b1   = (const float*)d_in[13];
    const float* g1   = (const float*)d_in[14];
    const float* be1  = (const float*)d_in[15];
    const float* m1   = (const float*)d_in[16];
    const float* v1   = (const float*)d_in[17];
    const float* Wc   = (const float*)d_in[18];
    const float* bc   = (const float*)d_in[19];
    float* out = (float*)d_out;

    const int N = N_NODES, E = E_EDGES;
    const int* srcp = ei;        // edge_index[0]
    const int* dstp = ei + E;    // edge_index[1]

    // workspace carve-up (16B-aligned chunks)
    char* p = (char*)d_ws;
    _Float16* xlf = (_Float16*)p; p += (size_t)M_PAD * HC * 2;   // xl table [M_PAD,256] f16
    _Float16* xrf = (_Float16*)p; p += (size_t)M_PAD * HC * 2;   // xr table [M_PAD,256] f16
    _Float16* h0  = (_Float16*)p; p += (size_t)M_PAD * HC * 2;   // h0 [M_PAD,256] f16
    _Float16* W0lt = (_Float16*)p; p += (size_t)HC * IN_CH * 2;  // Wt of Wl0 [256][128]
    _Float16* W0rt = (_Float16*)p; p += (size_t)HC * IN_CH * 2;
    _Float16* W1lt = (_Float16*)p; p += (size_t)HC * HC * 2;     // Wt of Wl1 [256][256]
    _Float16* W1rt = (_Float16*)p; p += (size_t)HC * HC * 2;
    int* deg      = (int*)p;
    int* row_ptr  = deg + N;
    int* cursor   = row_ptr + (N + 1);
    int* partials = cursor + N;
    int* csr_src  = partials + ((SCAN_B + 3) & ~3);   // E+N entries

    // CSR build (by dst)
    k_init_deg<<<(N + 255) / 256, 256, 0, stream>>>(deg, N);
    k_hist<<<(E + 255) / 256, 256, 0, stream>>>(dstp, deg, E);
    k_scan_local<<<SCAN_B, 256, 0, stream>>>(deg, row_ptr, partials, N);
    k_scan_part<<<1, 128, 0, stream>>>(partials, row_ptr + N);
    k_scan_add<<<(N + 255) / 256, 256, 0, stream>>>(row_ptr, cursor, partials, N);
    k_fill<<<(E + N + 255) / 256, 256, 0, stream>>>(srcp, dstp, cursor, csr_src, E, N);

    // weight prep (single fused launch)
    k_split_w4<<<768, 256, 0, stream>>>(Wl0, Wr0, Wl1, Wr1, W0lt, W0rt, W1lt, W1rt);

    dim3 ggrid(M_PAD / 128, 2, 2);
    // layer 0 projections: xl0 = x@Wl0, xr0 = x@Wr0 (f32 A converted in staging)
    k_gemm_mfma<<<ggrid, 256, 0, stream>>>(nullptr, x, W0lt, W0rt, xlf, xrf, IN_CH);
    // layer 0 edge pass + BN + ELU -> h0 (f16)
    k_edge0<<<N / 4, 256, 0, stream>>>(xlf, xrf, att0, row_ptr, csr_src,
                                       b0, g0, be0, m0, v0, h0);
    // layer 1 projections: xl1 = h0@Wl1, xr1 = h0@Wr1
    k_gemm_mfma<<<ggrid, 256, 0, stream>>>(h0, nullptr, W1lt, W1rt, xlf, xrf, HC);
    // layer 1 edge pass + head-mean + BN + classifier -> out
    k_edge1<<<N / 4, 256, 0, stream>>>(xlf, xrf, att1, row_ptr, csr_src,
                                       b1, g1, be1, m1, v1, Wc, bc, out);
}